// Round 1
// baseline (801.758 us; speedup 1.0000x reference)
//
#include <hip/hip_runtime.h>
#include <hip/hip_bf16.h>
#include <cstdint>

typedef unsigned short u16;
typedef __bf16 bf16x8 __attribute__((ext_vector_type(8)));
typedef float f32x4 __attribute__((ext_vector_type(4)));

#define SEQ 1024
#define HID 4096
#define NHQ 32
#define NKVH 8
#define HDIM 128
#define NB 2
#define NROWS (NB*SEQ)

static __device__ __forceinline__ u16 f2bf(float x) {
  __hip_bfloat16 h = __float2bfloat16(x);
  return *reinterpret_cast<u16*>(&h);
}

static __device__ __forceinline__ void gload16(const void* g, void* l) {
  __builtin_amdgcn_global_load_lds((__attribute__((address_space(1))) void*)(void*)g,
                                   (__attribute__((address_space(3))) void*)l, 16, 0, 0);
}

// ---------------- weight abs-sum (pass 1) ----------------
__global__ __launch_bounds__(256) void k_abssum(const float* __restrict__ w, long n4,
                                                float* __restrict__ partial) {
  float s = 0.f;
  long stride = (long)gridDim.x * 256;
  const float4* w4 = (const float4*)w;
  for (long j = (long)blockIdx.x*256 + threadIdx.x; j < n4; j += stride) {
    float4 v = w4[j];
    s += fabsf(v.x) + fabsf(v.y) + fabsf(v.z) + fabsf(v.w);
  }
  #pragma unroll
  for (int off = 1; off < 64; off <<= 1) s += __shfl_xor(s, off);
  __shared__ float red[4];
  if ((threadIdx.x & 63) == 0) red[threadIdx.x >> 6] = s;
  __syncthreads();
  if (threadIdx.x == 0) partial[blockIdx.x] = red[0] + red[1] + red[2] + red[3];
}

// ---------------- weight scales (pass 2) ----------------
__global__ __launch_bounds__(256) void k_wscale(const float* __restrict__ partial,
                                                float* __restrict__ wsc) {
  __shared__ float red[4];
  const float nelem[4] = {16777216.f, 4194304.f, 4194304.f, 16777216.f};
  for (int wi = 0; wi < 4; ++wi) {
    float s = 0.f;
    for (int j = threadIdx.x; j < 1024; j += 256) s += partial[wi*1024 + j];
    #pragma unroll
    for (int off = 1; off < 64; off <<= 1) s += __shfl_xor(s, off);
    if ((threadIdx.x & 63) == 0) red[threadIdx.x >> 6] = s;
    __syncthreads();
    if (threadIdx.x == 0) wsc[wi] = fmaxf((red[0]+red[1]+red[2]+red[3]) / nelem[wi], 1e-5f);
    __syncthreads();
  }
}

// ---------------- ternary weight quantize -> bf16 ----------------
__global__ __launch_bounds__(256) void k_quantw(const float* __restrict__ w, u16* __restrict__ wq,
                                                const float* __restrict__ wsc, int idx) {
  long j = (long)blockIdx.x*256 + threadIdx.x;  // one float4 per thread, exact grid
  float inv = 1.0f / wsc[idx];
  float4 v = ((const float4*)w)[j];
  ushort4 o;
  o.x = f2bf(fminf(fmaxf(rintf(v.x*inv), -1.f), 1.f));
  o.y = f2bf(fminf(fmaxf(rintf(v.y*inv), -1.f), 1.f));
  o.z = f2bf(fminf(fmaxf(rintf(v.z*inv), -1.f), 1.f));
  o.w = f2bf(fminf(fmaxf(rintf(v.w*inv), -1.f), 1.f));
  ((ushort4*)wq)[j] = o;
}

// ---------------- per-row activation quantize (hidden) ----------------
__global__ __launch_bounds__(256) void k_actq(const float* __restrict__ x, u16* __restrict__ xq,
                                              float* __restrict__ xs) {
  long row = blockIdx.x;
  const float4* xr = (const float4*)(x + row*HID);
  float4 v[4];
  float am = 0.f;
  #pragma unroll
  for (int j = 0; j < 4; ++j) {
    v[j] = xr[j*256 + threadIdx.x];
    am = fmaxf(am, fmaxf(fmaxf(fabsf(v[j].x), fabsf(v[j].y)), fmaxf(fabsf(v[j].z), fabsf(v[j].w))));
  }
  #pragma unroll
  for (int off = 1; off < 64; off <<= 1) am = fmaxf(am, __shfl_xor(am, off));
  __shared__ float red[4];
  if ((threadIdx.x & 63) == 0) red[threadIdx.x >> 6] = am;
  __syncthreads();
  am = fmaxf(fmaxf(red[0], red[1]), fmaxf(red[2], red[3]));
  float amc = fmaxf(am, 1e-5f);
  float s = 127.0f / amc;
  ushort4* oq = (ushort4*)(xq + row*HID);
  #pragma unroll
  for (int j = 0; j < 4; ++j) {
    ushort4 o;
    o.x = f2bf(fminf(fmaxf(rintf(v[j].x*s), -128.f), 127.f));
    o.y = f2bf(fminf(fmaxf(rintf(v[j].y*s), -128.f), 127.f));
    o.z = f2bf(fminf(fmaxf(rintf(v[j].z*s), -128.f), 127.f));
    o.w = f2bf(fminf(fmaxf(rintf(v[j].w*s), -128.f), 127.f));
    oq[j*256 + threadIdx.x] = o;
  }
  if (threadIdx.x == 0) xs[row] = amc / 127.0f;
}

// ---------------- GEMM: C[M][N] = A[M][K] * W[N][K]^T * arow[m] * wsc ----------------
__global__ __launch_bounds__(256) void k_gemm(const u16* __restrict__ A, const u16* __restrict__ W,
                                              float* __restrict__ C, const float* __restrict__ arow,
                                              const float* __restrict__ wsc, int widx,
                                              int M, int N, int K) {
  __shared__ u16 As[128*32] __attribute__((aligned(16)));
  __shared__ u16 Ws_[128*32] __attribute__((aligned(16)));
  int t = threadIdx.x;
  int bm = blockIdx.y, bn = blockIdx.x;
  const u16* Ab = A + (long)bm*128*K;
  const u16* Wb = W + (long)bn*128*K;
  int lane = t & 63, wid = t >> 6;
  int wr = wid >> 1, wc = wid & 1;
  int lrow = lane & 15, l8 = lane >> 4;
  f32x4 zero = {0.f, 0.f, 0.f, 0.f};
  f32x4 acc[4][4];
  #pragma unroll
  for (int mi = 0; mi < 4; ++mi)
    #pragma unroll
    for (int ni = 0; ni < 4; ++ni) acc[mi][ni] = zero;

  int f0 = t, f1 = t + 256;
  int r0 = f0 >> 2, c0 = (f0 & 3) * 8;
  int r1 = f1 >> 2, c1 = (f1 & 3) * 8;
  int nk = K >> 5;
  for (int kt = 0; kt < nk; ++kt) {
    gload16(Ab + (long)r0*K + kt*32 + c0, &As[f0*8]);
    gload16(Ab + (long)r1*K + kt*32 + c1, &As[f1*8]);
    gload16(Wb + (long)r0*K + kt*32 + c0, &Ws_[f0*8]);
    gload16(Wb + (long)r1*K + kt*32 + c1, &Ws_[f1*8]);
    __syncthreads();
    bf16x8 af[4], bfr[4];
    #pragma unroll
    for (int mi = 0; mi < 4; ++mi) af[mi] = *(const bf16x8*)&As[(wr*64 + mi*16 + lrow)*32 + l8*8];
    #pragma unroll
    for (int ni = 0; ni < 4; ++ni) bfr[ni] = *(const bf16x8*)&Ws_[(wc*64 + ni*16 + lrow)*32 + l8*8];
    #pragma unroll
    for (int mi = 0; mi < 4; ++mi)
      #pragma unroll
      for (int ni = 0; ni < 4; ++ni)
        acc[mi][ni] = __builtin_amdgcn_mfma_f32_16x16x32_bf16(af[mi], bfr[ni], acc[mi][ni], 0, 0, 0);
    __syncthreads();
  }
  float ws = wsc[widx];
  #pragma unroll
  for (int mi = 0; mi < 4; ++mi)
    #pragma unroll
    for (int r = 0; r < 4; ++r) {
      int row = bm*128 + wr*64 + mi*16 + l8*4 + r;
      float sc = arow[row] * ws;
      #pragma unroll
      for (int ni = 0; ni < 4; ++ni) {
        int col = bn*128 + wc*64 + ni*16 + lrow;
        C[(long)row*N + col] = acc[mi][ni][r] * sc;
      }
    }
}

// ---------------- rope tables ----------------
__global__ __launch_bounds__(256) void k_ropetab(float* __restrict__ cosb, float* __restrict__ sinb) {
  int idx = blockIdx.x*256 + threadIdx.x;       // 1024*64
  int s = idx >> 6, i = idx & 63;
  float e = (2.0f * (float)i) / 128.0f;
  float inv = 1.0f / powf(500000.0f, e);
  float f = (float)s * inv;
  cosb[idx] = cosf(f);
  sinb[idx] = sinf(f);
}

// ---------------- rope apply + layout to [b][h][s][d] bf16 ----------------
__global__ __launch_bounds__(256) void k_rope(const float* __restrict__ src, u16* __restrict__ dst,
                                              const float* __restrict__ cosb, const float* __restrict__ sinb,
                                              int nh, long total) {
  long idx = (long)blockIdx.x*256 + threadIdx.x;   // (b*s*nh*64)
  if (idx >= total) return;
  int i = (int)(idx & 63);
  long r1 = idx >> 6;
  int h = (int)(r1 % nh);
  long bs = r1 / nh;
  int s = (int)(bs & (SEQ-1));
  int b = (int)(bs >> 10);
  const float* p = src + bs*((long)nh*HDIM) + h*HDIM + 2*i;
  float a = p[0], bb = p[1];
  float c = cosb[(s<<6) + i], sn = sinb[(s<<6) + i];
  long o = (((long)b*nh + h)*SEQ + s)*HDIM + 2*i;
  dst[o]   = f2bf(a*c - bb*sn);
  dst[o+1] = f2bf(a*sn + bb*c);
}

// ---------------- V convert + transpose to [b][h][d][s] bf16 ----------------
__global__ __launch_bounds__(256) void k_vt(const float* __restrict__ v, u16* __restrict__ vt) {
  long idx = (long)blockIdx.x*256 + threadIdx.x;   // B*8*128*1024
  int s = (int)(idx & (SEQ-1));
  long r = idx >> 10;
  int d = (int)(r & (HDIM-1)); r >>= 7;
  int h = (int)(r & (NKVH-1));
  int b = (int)(r >> 3);
  vt[idx] = f2bf(v[(((long)b*SEQ + s)*NKVH + h)*HDIM + d]);
}

// ---------------- causal GQA flash attention ----------------
__global__ __launch_bounds__(256) void k_attn(const u16* __restrict__ qb, const u16* __restrict__ kb,
                                              const u16* __restrict__ vt, float* __restrict__ ao) {
  int qt = blockIdx.x, h = blockIdx.y, b = blockIdx.z;
  int t = threadIdx.x, lane = t & 63, wid = t >> 6;
  int lrow = lane & 15, l8 = lane >> 4;
  int q0 = qt*64 + wid*16;
  const u16* qp = qb + (((long)(b*NHQ + h))*SEQ + q0)*HDIM;
  const u16* kp = kb + ((long)(b*NKVH + (h >> 2)))*SEQ*HDIM;
  const u16* vp = vt + ((long)(b*NKVH + (h >> 2)))*HDIM*SEQ;
  bf16x8 qf[4];
  #pragma unroll
  for (int ks = 0; ks < 4; ++ks) qf[ks] = *(const bf16x8*)&qp[lrow*HDIM + ks*32 + l8*8];
  f32x4 zero = {0.f, 0.f, 0.f, 0.f};
  f32x4 o[8];
  #pragma unroll
  for (int f = 0; f < 8; ++f) o[f] = zero;
  float m[4], ll[4];
  #pragma unroll
  for (int r = 0; r < 4; ++r) { m[r] = -1e30f; ll[r] = 0.f; }
  __shared__ u16 Ps[4][16][72] __attribute__((aligned(16)));

  for (int j = 0; j <= qt; ++j) {
    f32x4 sc[4];
    #pragma unroll
    for (int ni = 0; ni < 4; ++ni) sc[ni] = zero;
    #pragma unroll
    for (int ni = 0; ni < 4; ++ni)
      #pragma unroll
      for (int ks = 0; ks < 4; ++ks) {
        bf16x8 kf = *(const bf16x8*)&kp[((long)(j*64 + ni*16 + lrow))*HDIM + ks*32 + l8*8];
        sc[ni] = __builtin_amdgcn_mfma_f32_16x16x32_bf16(qf[ks], kf, sc[ni], 0, 0, 0);
      }
    const float scale = 0.08838834764831845f;    // 1/sqrt(128)
    float pm[4] = {-1e30f, -1e30f, -1e30f, -1e30f};
    float pv[4][4];
    bool diag = (j == qt);
    #pragma unroll
    for (int ni = 0; ni < 4; ++ni) {
      int kv = j*64 + ni*16 + lrow;
      #pragma unroll
      for (int r = 0; r < 4; ++r) {
        int qr = q0 + l8*4 + r;
        float val = sc[ni][r] * scale;
        if (diag && kv > qr) val = -1e30f;
        pv[ni][r] = val;
        pm[r] = fmaxf(pm[r], val);
      }
    }
    #pragma unroll
    for (int r = 0; r < 4; ++r) {
      #pragma unroll
      for (int off = 1; off < 16; off <<= 1) pm[r] = fmaxf(pm[r], __shfl_xor(pm[r], off));
    }
    float fr[4], rs[4];
    #pragma unroll
    for (int r = 0; r < 4; ++r) {
      float nm = fmaxf(m[r], pm[r]);
      fr[r] = __expf(m[r] - nm);
      m[r] = nm; rs[r] = 0.f;
    }
    #pragma unroll
    for (int ni = 0; ni < 4; ++ni)
      #pragma unroll
      for (int r = 0; r < 4; ++r) {
        float p = __expf(pv[ni][r] - m[r]);
        pv[ni][r] = p; rs[r] += p;
      }
    #pragma unroll
    for (int r = 0; r < 4; ++r) {
      #pragma unroll
      for (int off = 1; off < 16; off <<= 1) rs[r] += __shfl_xor(rs[r], off);
      ll[r] = ll[r]*fr[r] + rs[r];
    }
    #pragma unroll
    for (int f = 0; f < 8; ++f) {
      o[f][0] *= fr[0]; o[f][1] *= fr[1]; o[f][2] *= fr[2]; o[f][3] *= fr[3];
    }
    #pragma unroll
    for (int ni = 0; ni < 4; ++ni)
      #pragma unroll
      for (int r = 0; r < 4; ++r)
        Ps[wid][l8*4 + r][ni*16 + lrow] = f2bf(pv[ni][r]);
    bf16x8 pf0 = *(const bf16x8*)&Ps[wid][lrow][l8*8];
    bf16x8 pf1 = *(const bf16x8*)&Ps[wid][lrow][32 + l8*8];
    #pragma unroll
    for (int f = 0; f < 8; ++f) {
      bf16x8 vf0 = *(const bf16x8*)&vp[((long)(f*16 + lrow))*SEQ + j*64 + l8*8];
      bf16x8 vf1 = *(const bf16x8*)&vp[((long)(f*16 + lrow))*SEQ + j*64 + 32 + l8*8];
      o[f] = __builtin_amdgcn_mfma_f32_16x16x32_bf16(pf0, vf0, o[f], 0, 0, 0);
      o[f] = __builtin_amdgcn_mfma_f32_16x16x32_bf16(pf1, vf1, o[f], 0, 0, 0);
    }
  }
  float invl[4];
  #pragma unroll
  for (int r = 0; r < 4; ++r) invl[r] = 1.0f / ll[r];
  #pragma unroll
  for (int f = 0; f < 8; ++f)
    #pragma unroll
    for (int r = 0; r < 4; ++r) {
      long row = (long)b*SEQ + q0 + l8*4 + r;
      ao[row*HID + h*HDIM + f*16 + lrow] = o[f][r] * invl[r];
    }
}

// ---------------- fused rmsnorm + act quant ----------------
__global__ __launch_bounds__(256) void k_rmsq(const float* __restrict__ x, const float* __restrict__ w,
                                              u16* __restrict__ yq, float* __restrict__ ys) {
  long row = blockIdx.x;
  const float4* xr = (const float4*)(x + row*HID);
  const float4* wr = (const float4*)w;
  float4 v[4];
  float ss = 0.f;
  #pragma unroll
  for (int j = 0; j < 4; ++j) {
    v[j] = xr[j*256 + threadIdx.x];
    ss += v[j].x*v[j].x + v[j].y*v[j].y + v[j].z*v[j].z + v[j].w*v[j].w;
  }
  #pragma unroll
  for (int off = 1; off < 64; off <<= 1) ss += __shfl_xor(ss, off);
  __shared__ float red[4];
  if ((threadIdx.x & 63) == 0) red[threadIdx.x >> 6] = ss;
  __syncthreads();
  ss = red[0] + red[1] + red[2] + red[3];
  __syncthreads();
  float rn = rsqrtf(ss / (float)HID + 1e-6f);
  float4 y[4];
  float am = 0.f;
  #pragma unroll
  for (int j = 0; j < 4; ++j) {
    float4 wv = wr[j*256 + threadIdx.x];
    y[j].x = v[j].x * rn * wv.x; y[j].y = v[j].y * rn * wv.y;
    y[j].z = v[j].z * rn * wv.z; y[j].w = v[j].w * rn * wv.w;
    am = fmaxf(am, fmaxf(fmaxf(fabsf(y[j].x), fabsf(y[j].y)), fmaxf(fabsf(y[j].z), fabsf(y[j].w))));
  }
  #pragma unroll
  for (int off = 1; off < 64; off <<= 1) am = fmaxf(am, __shfl_xor(am, off));
  if ((threadIdx.x & 63) == 0) red[threadIdx.x >> 6] = am;
  __syncthreads();
  am = fmaxf(fmaxf(red[0], red[1]), fmaxf(red[2], red[3]));
  float amc = fmaxf(am, 1e-5f);
  float s = 127.0f / amc;
  ushort4* oq = (ushort4*)(yq + row*HID);
  #pragma unroll
  for (int j = 0; j < 4; ++j) {
    ushort4 o;
    o.x = f2bf(fminf(fmaxf(rintf(y[j].x*s), -128.f), 127.f));
    o.y = f2bf(fminf(fmaxf(rintf(y[j].y*s), -128.f), 127.f));
    o.z = f2bf(fminf(fmaxf(rintf(y[j].z*s), -128.f), 127.f));
    o.w = f2bf(fminf(fmaxf(rintf(y[j].w*s), -128.f), 127.f));
    oq[j*256 + threadIdx.x] = o;
  }
  if (threadIdx.x == 0) ys[row] = amc / 127.0f;
}

extern "C" void kernel_launch(void* const* d_in, const int* in_sizes, int n_in,
                              void* d_out, int out_size, void* d_ws, size_t ws_size,
                              hipStream_t stream) {
  const float* hs    = (const float*)d_in[0];
  const float* w_q   = (const float*)d_in[2];
  const float* w_k   = (const float*)d_in[3];
  const float* w_v   = (const float*)d_in[4];
  const float* w_o   = (const float*)d_in[5];
  const float* subln = (const float*)d_in[6];

  char* ws = (char*)d_ws;
  u16*   wqq = (u16*)(ws + 0);                    // 33554432 B
  u16*   wqk = (u16*)(ws + 33554432L);            // 8388608
  u16*   wqv = (u16*)(ws + 41943040L);            // 8388608
  u16*   wqo = (u16*)(ws + 50331648L);            // 33554432
  u16*   xq  = (u16*)(ws + 83886080L);            // 16777216
  float* qf  = (float*)(ws + 100663296L);         // 33554432 (later: ao)
  float* kf  = (float*)(ws + 134217728L);         // 8388608  (later: yq lo)
  float* vf  = (float*)(ws + 142606336L);         // 8388608  (later: yq hi)
  u16*   qb  = (u16*)(ws + 150994944L);           // 16777216
  u16*   kb  = (u16*)(ws + 167772160L);           // 4194304
  u16*   vtb = (u16*)(ws + 171966464L);           // 4194304
  float* cosb= (float*)(ws + 176160768L);         // 262144
  float* sinb= (float*)(ws + 176422912L);         // 262144
  float* xs  = (float*)(ws + 176685056L);         // 8192
  float* ys  = (float*)(ws + 176693248L);         // 8192
  float* wsc = (float*)(ws + 176701440L);         // 16
  float* par = (float*)(ws + 176701696L);         // 16384
  float* ao  = qf;
  u16*   yq  = (u16*)kf;
  float* out = (float*)d_out;

  // 1. weight scales
  k_abssum<<<1024, 256, 0, stream>>>(w_q, 16777216L/4, par + 0*1024);
  k_abssum<<<1024, 256, 0, stream>>>(w_k,  4194304L/4, par + 1*1024);
  k_abssum<<<1024, 256, 0, stream>>>(w_v,  4194304L/4, par + 2*1024);
  k_abssum<<<1024, 256, 0, stream>>>(w_o, 16777216L/4, par + 3*1024);
  k_wscale<<<1, 256, 0, stream>>>(par, wsc);

  // 2. quantize weights (ternary, bf16)
  k_quantw<<<16384, 256, 0, stream>>>(w_q, wqq, wsc, 0);
  k_quantw<<< 4096, 256, 0, stream>>>(w_k, wqk, wsc, 1);
  k_quantw<<< 4096, 256, 0, stream>>>(w_v, wqv, wsc, 2);
  k_quantw<<<16384, 256, 0, stream>>>(w_o, wqo, wsc, 3);

  // 3. act quant of hidden
  k_actq<<<NROWS, 256, 0, stream>>>(hs, xq, xs);

  // 4. QKV GEMMs
  k_gemm<<<dim3(32, 16), 256, 0, stream>>>(xq, wqq, qf, xs, wsc, 0, NROWS, 4096, 4096);
  k_gemm<<<dim3(8, 16),  256, 0, stream>>>(xq, wqk, kf, xs, wsc, 1, NROWS, 1024, 4096);
  k_gemm<<<dim3(8, 16),  256, 0, stream>>>(xq, wqv, vf, xs, wsc, 2, NROWS, 1024, 4096);

  // 5. rope tables + apply + v transpose
  k_ropetab<<<256, 256, 0, stream>>>(cosb, sinb);
  k_rope<<<16384, 256, 0, stream>>>(qf, qb, cosb, sinb, NHQ,  (long)NB*SEQ*NHQ*64);
  k_rope<<< 4096, 256, 0, stream>>>(kf, kb, cosb, sinb, NKVH, (long)NB*SEQ*NKVH*64);
  k_vt<<<8192, 256, 0, stream>>>(vf, vtb);

  // 6. attention (writes ao, aliases qf — qf dead after rope)
  k_attn<<<dim3(16, 32, 2), 256, 0, stream>>>(qb, kb, vtb, ao);

  // 7. rmsnorm + act quant (writes yq over kf/vf — dead after rope/vt)
  k_rmsq<<<NROWS, 256, 0, stream>>>(ao, subln, yq, ys);

  // 8. output GEMM
  k_gemm<<<dim3(32, 16), 256, 0, stream>>>(yq, wqo, out, ys, wsc, 3, NROWS, 4096, 4096);
}

// Round 2
// 499.211 us; speedup vs baseline: 1.6061x; 1.6061x over previous
//
#include <hip/hip_runtime.h>
#include <hip/hip_bf16.h>
#include <cstdint>

typedef unsigned short u16;
typedef __bf16 bf16x8 __attribute__((ext_vector_type(8)));
typedef float f32x4 __attribute__((ext_vector_type(4)));

#define SEQ 1024
#define HID 4096
#define NHQ 32
#define NKVH 8
#define HDIM 128
#define NB 2
#define NROWS (NB*SEQ)

static __device__ __forceinline__ u16 f2bf(float x) {
  __hip_bfloat16 h = __float2bfloat16(x);
  return *reinterpret_cast<u16*>(&h);
}

static __device__ __forceinline__ void gload16(const void* g, void* l) {
  __builtin_amdgcn_global_load_lds((__attribute__((address_space(1))) void*)(void*)g,
                                   (__attribute__((address_space(3))) void*)l, 16, 0, 0);
}

// ---------------- weight abs-sum (pass 1) ----------------
__global__ __launch_bounds__(256) void k_abssum(const float* __restrict__ w, long n4,
                                                float* __restrict__ partial) {
  float s = 0.f;
  long stride = (long)gridDim.x * 256;
  const float4* w4 = (const float4*)w;
  for (long j = (long)blockIdx.x*256 + threadIdx.x; j < n4; j += stride) {
    float4 v = w4[j];
    s += fabsf(v.x) + fabsf(v.y) + fabsf(v.z) + fabsf(v.w);
  }
  #pragma unroll
  for (int off = 1; off < 64; off <<= 1) s += __shfl_xor(s, off);
  __shared__ float red[4];
  if ((threadIdx.x & 63) == 0) red[threadIdx.x >> 6] = s;
  __syncthreads();
  if (threadIdx.x == 0) partial[blockIdx.x] = red[0] + red[1] + red[2] + red[3];
}

// ---------------- weight scales (pass 2) ----------------
__global__ __launch_bounds__(256) void k_wscale(const float* __restrict__ partial,
                                                float* __restrict__ wsc) {
  __shared__ float red[4];
  const float nelem[4] = {16777216.f, 4194304.f, 4194304.f, 16777216.f};
  for (int wi = 0; wi < 4; ++wi) {
    float s = 0.f;
    for (int j = threadIdx.x; j < 1024; j += 256) s += partial[wi*1024 + j];
    #pragma unroll
    for (int off = 1; off < 64; off <<= 1) s += __shfl_xor(s, off);
    if ((threadIdx.x & 63) == 0) red[threadIdx.x >> 6] = s;
    __syncthreads();
    if (threadIdx.x == 0) wsc[wi] = fmaxf((red[0]+red[1]+red[2]+red[3]) / nelem[wi], 1e-5f);
    __syncthreads();
  }
}

// ---------------- ternary weight quantize -> bf16 ----------------
__global__ __launch_bounds__(256) void k_quantw(const float* __restrict__ w, u16* __restrict__ wq,
                                                const float* __restrict__ wsc, int idx) {
  long j = (long)blockIdx.x*256 + threadIdx.x;
  float inv = 1.0f / wsc[idx];
  float4 v = ((const float4*)w)[j];
  ushort4 o;
  o.x = f2bf(fminf(fmaxf(rintf(v.x*inv), -1.f), 1.f));
  o.y = f2bf(fminf(fmaxf(rintf(v.y*inv), -1.f), 1.f));
  o.z = f2bf(fminf(fmaxf(rintf(v.z*inv), -1.f), 1.f));
  o.w = f2bf(fminf(fmaxf(rintf(v.w*inv), -1.f), 1.f));
  ((ushort4*)wq)[j] = o;
}

// ---------------- per-row activation quantize (hidden) ----------------
__global__ __launch_bounds__(256) void k_actq(const float* __restrict__ x, u16* __restrict__ xq,
                                              float* __restrict__ xs) {
  long row = blockIdx.x;
  const float4* xr = (const float4*)(x + row*HID);
  float4 v[4];
  float am = 0.f;
  #pragma unroll
  for (int j = 0; j < 4; ++j) {
    v[j] = xr[j*256 + threadIdx.x];
    am = fmaxf(am, fmaxf(fmaxf(fabsf(v[j].x), fabsf(v[j].y)), fmaxf(fabsf(v[j].z), fabsf(v[j].w))));
  }
  #pragma unroll
  for (int off = 1; off < 64; off <<= 1) am = fmaxf(am, __shfl_xor(am, off));
  __shared__ float red[4];
  if ((threadIdx.x & 63) == 0) red[threadIdx.x >> 6] = am;
  __syncthreads();
  am = fmaxf(fmaxf(red[0], red[1]), fmaxf(red[2], red[3]));
  float amc = fmaxf(am, 1e-5f);
  float s = 127.0f / amc;
  ushort4* oq = (ushort4*)(xq + row*HID);
  #pragma unroll
  for (int j = 0; j < 4; ++j) {
    ushort4 o;
    o.x = f2bf(fminf(fmaxf(rintf(v[j].x*s), -128.f), 127.f));
    o.y = f2bf(fminf(fmaxf(rintf(v[j].y*s), -128.f), 127.f));
    o.z = f2bf(fminf(fmaxf(rintf(v[j].z*s), -128.f), 127.f));
    o.w = f2bf(fminf(fmaxf(rintf(v[j].w*s), -128.f), 127.f));
    oq[j*256 + threadIdx.x] = o;
  }
  if (threadIdx.x == 0) xs[row] = amc / 127.0f;
}

// ---------------- GEMM: C[M][N] = A[M][K] * W[N][K]^T * arow[m] * wsc ----------------
__global__ __launch_bounds__(256) void k_gemm(const u16* __restrict__ A, const u16* __restrict__ W,
                                              float* __restrict__ C, const float* __restrict__ arow,
                                              const float* __restrict__ wsc, int widx,
                                              int M, int N, int K) {
  __shared__ u16 As[128*32] __attribute__((aligned(16)));
  __shared__ u16 Ws_[128*32] __attribute__((aligned(16)));
  int t = threadIdx.x;
  int bm = blockIdx.y, bn = blockIdx.x;
  const u16* Ab = A + (long)bm*128*K;
  const u16* Wb = W + (long)bn*128*K;
  int lane = t & 63, wid = t >> 6;
  int wr = wid >> 1, wc = wid & 1;
  int lrow = lane & 15, l8 = lane >> 4;
  f32x4 zero = {0.f, 0.f, 0.f, 0.f};
  f32x4 acc[4][4];
  #pragma unroll
  for (int mi = 0; mi < 4; ++mi)
    #pragma unroll
    for (int ni = 0; ni < 4; ++ni) acc[mi][ni] = zero;

  int f0 = t, f1 = t + 256;
  int r0 = f0 >> 2, c0 = (f0 & 3) * 8;
  int r1 = f1 >> 2, c1 = (f1 & 3) * 8;
  int nk = K >> 5;
  for (int kt = 0; kt < nk; ++kt) {
    gload16(Ab + (long)r0*K + kt*32 + c0, &As[f0*8]);
    gload16(Ab + (long)r1*K + kt*32 + c1, &As[f1*8]);
    gload16(Wb + (long)r0*K + kt*32 + c0, &Ws_[f0*8]);
    gload16(Wb + (long)r1*K + kt*32 + c1, &Ws_[f1*8]);
    __syncthreads();
    bf16x8 af[4], bfr[4];
    #pragma unroll
    for (int mi = 0; mi < 4; ++mi) af[mi] = *(const bf16x8*)&As[(wr*64 + mi*16 + lrow)*32 + l8*8];
    #pragma unroll
    for (int ni = 0; ni < 4; ++ni) bfr[ni] = *(const bf16x8*)&Ws_[(wc*64 + ni*16 + lrow)*32 + l8*8];
    #pragma unroll
    for (int mi = 0; mi < 4; ++mi)
      #pragma unroll
      for (int ni = 0; ni < 4; ++ni)
        acc[mi][ni] = __builtin_amdgcn_mfma_f32_16x16x32_bf16(af[mi], bfr[ni], acc[mi][ni], 0, 0, 0);
    __syncthreads();
  }
  float ws = wsc[widx];
  #pragma unroll
  for (int mi = 0; mi < 4; ++mi)
    #pragma unroll
    for (int r = 0; r < 4; ++r) {
      int row = bm*128 + wr*64 + mi*16 + l8*4 + r;
      float sc = arow[row] * ws;
      #pragma unroll
      for (int ni = 0; ni < 4; ++ni) {
        int col = bn*128 + wc*64 + ni*16 + lrow;
        C[(long)row*N + col] = acc[mi][ni][r] * sc;
      }
    }
}

// ---------------- fused K/V GEMM: z=0 -> K (fp32 row-major), z=1 -> V (bf16 transposed [b][h][d][s])
__global__ __launch_bounds__(256) void k_gemm_kv(const u16* __restrict__ A, const u16* __restrict__ Wk,
                                                 const u16* __restrict__ Wv, float* __restrict__ Ck,
                                                 u16* __restrict__ Vt, const float* __restrict__ arow,
                                                 const float* __restrict__ wsc) {
  const int K = 4096, N = 1024;
  __shared__ u16 As[128*32] __attribute__((aligned(16)));
  __shared__ u16 Ws_[128*32] __attribute__((aligned(16)));
  int t = threadIdx.x;
  int bm = blockIdx.y, bn = blockIdx.x;
  int isV = blockIdx.z;
  const u16* W = isV ? Wv : Wk;
  const u16* Ab = A + (long)bm*128*K;
  const u16* Wb = W + (long)bn*128*K;
  int lane = t & 63, wid = t >> 6;
  int wr = wid >> 1, wc = wid & 1;
  int lrow = lane & 15, l8 = lane >> 4;
  f32x4 zero = {0.f, 0.f, 0.f, 0.f};
  f32x4 acc[4][4];
  #pragma unroll
  for (int mi = 0; mi < 4; ++mi)
    #pragma unroll
    for (int ni = 0; ni < 4; ++ni) acc[mi][ni] = zero;

  int f0 = t, f1 = t + 256;
  int r0 = f0 >> 2, c0 = (f0 & 3) * 8;
  int r1 = f1 >> 2, c1 = (f1 & 3) * 8;
  for (int kt = 0; kt < (K >> 5); ++kt) {
    gload16(Ab + (long)r0*K + kt*32 + c0, &As[f0*8]);
    gload16(Ab + (long)r1*K + kt*32 + c1, &As[f1*8]);
    gload16(Wb + (long)r0*K + kt*32 + c0, &Ws_[f0*8]);
    gload16(Wb + (long)r1*K + kt*32 + c1, &Ws_[f1*8]);
    __syncthreads();
    bf16x8 af[4], bfr[4];
    #pragma unroll
    for (int mi = 0; mi < 4; ++mi) af[mi] = *(const bf16x8*)&As[(wr*64 + mi*16 + lrow)*32 + l8*8];
    #pragma unroll
    for (int ni = 0; ni < 4; ++ni) bfr[ni] = *(const bf16x8*)&Ws_[(wc*64 + ni*16 + lrow)*32 + l8*8];
    #pragma unroll
    for (int mi = 0; mi < 4; ++mi)
      #pragma unroll
      for (int ni = 0; ni < 4; ++ni)
        acc[mi][ni] = __builtin_amdgcn_mfma_f32_16x16x32_bf16(af[mi], bfr[ni], acc[mi][ni], 0, 0, 0);
    __syncthreads();
  }
  if (!isV) {
    float ws = wsc[1];
    #pragma unroll
    for (int mi = 0; mi < 4; ++mi)
      #pragma unroll
      for (int r = 0; r < 4; ++r) {
        int row = bm*128 + wr*64 + mi*16 + l8*4 + r;
        float sc = arow[row] * ws;
        #pragma unroll
        for (int ni = 0; ni < 4; ++ni) {
          int col = bn*128 + wc*64 + ni*16 + lrow;
          Ck[(long)row*N + col] = acc[mi][ni][r] * sc;
        }
      }
  } else {
    float ws = wsc[2];
    #pragma unroll
    for (int mi = 0; mi < 4; ++mi) {
      int row0 = bm*128 + wr*64 + mi*16 + l8*4;
      int bidx = row0 >> 10, s0 = row0 & 1023;
      #pragma unroll
      for (int ni = 0; ni < 4; ++ni) {
        int col = bn*128 + wc*64 + ni*16 + lrow;
        int hkv = col >> 7, d = col & 127;
        ushort4 o4;
        o4.x = f2bf(acc[mi][ni][0] * arow[row0+0] * ws);
        o4.y = f2bf(acc[mi][ni][1] * arow[row0+1] * ws);
        o4.z = f2bf(acc[mi][ni][2] * arow[row0+2] * ws);
        o4.w = f2bf(acc[mi][ni][3] * arow[row0+3] * ws);
        *(ushort4*)&Vt[(((long)bidx*NKVH + hkv)*HDIM + d)*SEQ + s0] = o4;
      }
    }
  }
}

// ---------------- rope tables ----------------
__global__ __launch_bounds__(256) void k_ropetab(float* __restrict__ cosb, float* __restrict__ sinb) {
  int idx = blockIdx.x*256 + threadIdx.x;
  int s = idx >> 6, i = idx & 63;
  float e = (2.0f * (float)i) / 128.0f;
  float inv = 1.0f / powf(500000.0f, e);
  float f = (float)s * inv;
  cosb[idx] = cosf(f);
  sinb[idx] = sinf(f);
}

// ---------------- rope apply + layout to [b][h][s][d] bf16 ----------------
__global__ __launch_bounds__(256) void k_rope(const float* __restrict__ src, u16* __restrict__ dst,
                                              const float* __restrict__ cosb, const float* __restrict__ sinb,
                                              int nh, long total) {
  long idx = (long)blockIdx.x*256 + threadIdx.x;
  if (idx >= total) return;
  int i = (int)(idx & 63);
  long r1 = idx >> 6;
  int h = (int)(r1 % nh);
  long bs = r1 / nh;
  int s = (int)(bs & (SEQ-1));
  int b = (int)(bs >> 10);
  const float* p = src + bs*((long)nh*HDIM) + h*HDIM + 2*i;
  float a = p[0], bb = p[1];
  float c = cosb[(s<<6) + i], sn = sinb[(s<<6) + i];
  long o = (((long)b*nh + h)*SEQ + s)*HDIM + 2*i;
  dst[o]   = f2bf(a*c - bb*sn);
  dst[o+1] = f2bf(a*sn + bb*c);
}

// ---------------- causal GQA flash attention, LDS-staged, causal-paired ----------------
// grid (8, 32, 2): blockIdx.x = qpair p -> processes qt=p then qt=15-p
__global__ __launch_bounds__(256) void k_attn(const u16* __restrict__ qb, const u16* __restrict__ kb,
                                              const u16* __restrict__ vt, float* __restrict__ ao) {
  int p = blockIdx.x, h = blockIdx.y, b = blockIdx.z;
  int t = threadIdx.x, lane = t & 63, wid = t >> 6;
  int lrow = lane & 15, l8 = lane >> 4;
  int x7 = lrow & 7;                      // row&7 for all read rows (rows = k*16 + lrow)

  __shared__ u16 Ks[2][64*128] __attribute__((aligned(16)));   // [kv row][d], XOR-swizzled chunks
  __shared__ u16 Vs[2][128*64] __attribute__((aligned(16)));   // [d][kv s], XOR-swizzled chunks
  __shared__ u16 Ps[4][16][72] __attribute__((aligned(16)));

  const u16* kp = kb + ((long)(b*NKVH + (h >> 2)))*SEQ*HDIM;
  const u16* vp = vt + ((long)(b*NKVH + (h >> 2)))*HDIM*SEQ;

  auto stageK = [&](int buf, int j) {
    const u16* src = kp + (long)j*64*HDIM;
    #pragma unroll
    for (int i = 0; i < 4; ++i) {
      int r0 = wid*16 + i*4;
      int row = r0 + (lane >> 4);
      int cg = (lane & 15) ^ (row & 7);
      gload16(src + (long)row*HDIM + cg*8, &Ks[buf][r0*HDIM]);
    }
  };
  auto stageV = [&](int buf, int j) {
    #pragma unroll
    for (int i = 0; i < 4; ++i) {
      int r0 = wid*32 + i*8;
      int row = r0 + (lane >> 3);
      int cg = (lane & 7) ^ (row & 7);
      gload16(vp + (long)row*SEQ + j*64 + cg*8, &Vs[buf][r0*64]);
    }
  };

  for (int phase = 0; phase < 2; ++phase) {
    int qt = phase ? (15 - p) : p;
    int q0 = qt*64 + wid*16;
    const u16* qp = qb + (((long)(b*NHQ + h))*SEQ + q0)*HDIM;
    bf16x8 qf[4];
    #pragma unroll
    for (int ks = 0; ks < 4; ++ks) qf[ks] = *(const bf16x8*)&qp[lrow*HDIM + ks*32 + l8*8];
    f32x4 zero = {0.f, 0.f, 0.f, 0.f};
    f32x4 o[8];
    #pragma unroll
    for (int f = 0; f < 8; ++f) o[f] = zero;
    float m[4], ll[4];
    #pragma unroll
    for (int r = 0; r < 4; ++r) { m[r] = -1e30f; ll[r] = 0.f; }

    int nj = qt + 1;
    stageK(0, 0); stageV(0, 0);
    __syncthreads();
    int cur = 0;
    for (int j = 0; j < nj; ++j) {
      if (j + 1 < nj) { stageK(cur ^ 1, j + 1); stageV(cur ^ 1, j + 1); }
      const u16* Kc = Ks[cur];
      const u16* Vc = Vs[cur];
      f32x4 sc4[4];
      #pragma unroll
      for (int ni = 0; ni < 4; ++ni) sc4[ni] = zero;
      __builtin_amdgcn_s_setprio(1);
      #pragma unroll
      for (int ni = 0; ni < 4; ++ni) {
        int row = ni*16 + lrow;
        #pragma unroll
        for (int ks = 0; ks < 4; ++ks) {
          int cl = (ks*4 + l8) ^ x7;
          bf16x8 kfr = *(const bf16x8*)&Kc[row*HDIM + cl*8];
          sc4[ni] = __builtin_amdgcn_mfma_f32_16x16x32_bf16(qf[ks], kfr, sc4[ni], 0, 0, 0);
        }
      }
      __builtin_amdgcn_s_setprio(0);
      const float scale = 0.08838834764831845f;
      float pm[4] = {-1e30f, -1e30f, -1e30f, -1e30f};
      float pv[4][4];
      bool diag = (j == qt);
      #pragma unroll
      for (int ni = 0; ni < 4; ++ni) {
        int kv = j*64 + ni*16 + lrow;
        #pragma unroll
        for (int r = 0; r < 4; ++r) {
          int qr = q0 + l8*4 + r;
          float val = sc4[ni][r] * scale;
          if (diag && kv > qr) val = -1e30f;
          pv[ni][r] = val;
          pm[r] = fmaxf(pm[r], val);
        }
      }
      #pragma unroll
      for (int r = 0; r < 4; ++r) {
        #pragma unroll
        for (int off = 1; off < 16; off <<= 1) pm[r] = fmaxf(pm[r], __shfl_xor(pm[r], off));
      }
      float fr[4], rs[4];
      #pragma unroll
      for (int r = 0; r < 4; ++r) {
        float nm = fmaxf(m[r], pm[r]);
        fr[r] = __expf(m[r] - nm);
        m[r] = nm; rs[r] = 0.f;
      }
      #pragma unroll
      for (int ni = 0; ni < 4; ++ni)
        #pragma unroll
        for (int r = 0; r < 4; ++r) {
          float pe = __expf(pv[ni][r] - m[r]);
          pv[ni][r] = pe; rs[r] += pe;
        }
      #pragma unroll
      for (int r = 0; r < 4; ++r) {
        #pragma unroll
        for (int off = 1; off < 16; off <<= 1) rs[r] += __shfl_xor(rs[r], off);
        ll[r] = ll[r]*fr[r] + rs[r];
      }
      #pragma unroll
      for (int f = 0; f < 8; ++f) {
        o[f][0] *= fr[0]; o[f][1] *= fr[1]; o[f][2] *= fr[2]; o[f][3] *= fr[3];
      }
      #pragma unroll
      for (int ni = 0; ni < 4; ++ni)
        #pragma unroll
        for (int r = 0; r < 4; ++r)
          Ps[wid][l8*4 + r][ni*16 + lrow] = f2bf(pv[ni][r]);
      bf16x8 pf0 = *(const bf16x8*)&Ps[wid][lrow][l8*8];
      bf16x8 pf1 = *(const bf16x8*)&Ps[wid][lrow][32 + l8*8];
      __builtin_amdgcn_s_setprio(1);
      #pragma unroll
      for (int f = 0; f < 8; ++f) {
        int d = f*16 + lrow;
        bf16x8 v0 = *(const bf16x8*)&Vc[d*64 + ((l8) ^ x7)*8];
        bf16x8 v1 = *(const bf16x8*)&Vc[d*64 + ((4 + l8) ^ x7)*8];
        o[f] = __builtin_amdgcn_mfma_f32_16x16x32_bf16(pf0, v0, o[f], 0, 0, 0);
        o[f] = __builtin_amdgcn_mfma_f32_16x16x32_bf16(pf1, v1, o[f], 0, 0, 0);
      }
      __builtin_amdgcn_s_setprio(0);
      __syncthreads();
      cur ^= 1;
    }
    float invl[4];
    #pragma unroll
    for (int r = 0; r < 4; ++r) invl[r] = 1.0f / ll[r];
    #pragma unroll
    for (int f = 0; f < 8; ++f)
      #pragma unroll
      for (int r = 0; r < 4; ++r) {
        long row = (long)b*SEQ + q0 + l8*4 + r;
        ao[row*HID + h*HDIM + f*16 + lrow] = o[f][r] * invl[r];
      }
    __syncthreads();
  }
}

// ---------------- fused rmsnorm + act quant ----------------
__global__ __launch_bounds__(256) void k_rmsq(const float* __restrict__ x, const float* __restrict__ w,
                                              u16* __restrict__ yq, float* __restrict__ ys) {
  long row = blockIdx.x;
  const float4* xr = (const float4*)(x + row*HID);
  const float4* wr = (const float4*)w;
  float4 v[4];
  float ss = 0.f;
  #pragma unroll
  for (int j = 0; j < 4; ++j) {
    v[j] = xr[j*256 + threadIdx.x];
    ss += v[j].x*v[j].x + v[j].y*v[j].y + v[j].z*v[j].z + v[j].w*v[j].w;
  }
  #pragma unroll
  for (int off = 1; off < 64; off <<= 1) ss += __shfl_xor(ss, off);
  __shared__ float red[4];
  if ((threadIdx.x & 63) == 0) red[threadIdx.x >> 6] = ss;
  __syncthreads();
  ss = red[0] + red[1] + red[2] + red[3];
  __syncthreads();
  float rn = rsqrtf(ss / (float)HID + 1e-6f);
  float4 y[4];
  float am = 0.f;
  #pragma unroll
  for (int j = 0; j < 4; ++j) {
    float4 wv = wr[j*256 + threadIdx.x];
    y[j].x = v[j].x * rn * wv.x; y[j].y = v[j].y * rn * wv.y;
    y[j].z = v[j].z * rn * wv.z; y[j].w = v[j].w * rn * wv.w;
    am = fmaxf(am, fmaxf(fmaxf(fabsf(y[j].x), fabsf(y[j].y)), fmaxf(fabsf(y[j].z), fabsf(y[j].w))));
  }
  #pragma unroll
  for (int off = 1; off < 64; off <<= 1) am = fmaxf(am, __shfl_xor(am, off));
  if ((threadIdx.x & 63) == 0) red[threadIdx.x >> 6] = am;
  __syncthreads();
  am = fmaxf(fmaxf(red[0], red[1]), fmaxf(red[2], red[3]));
  float amc = fmaxf(am, 1e-5f);
  float s = 127.0f / amc;
  ushort4* oq = (ushort4*)(yq + row*HID);
  #pragma unroll
  for (int j = 0; j < 4; ++j) {
    ushort4 o;
    o.x = f2bf(fminf(fmaxf(rintf(y[j].x*s), -128.f), 127.f));
    o.y = f2bf(fminf(fmaxf(rintf(y[j].y*s), -128.f), 127.f));
    o.z = f2bf(fminf(fmaxf(rintf(y[j].z*s), -128.f), 127.f));
    o.w = f2bf(fminf(fmaxf(rintf(y[j].w*s), -128.f), 127.f));
    oq[j*256 + threadIdx.x] = o;
  }
  if (threadIdx.x == 0) ys[row] = amc / 127.0f;
}

extern "C" void kernel_launch(void* const* d_in, const int* in_sizes, int n_in,
                              void* d_out, int out_size, void* d_ws, size_t ws_size,
                              hipStream_t stream) {
  const float* hs    = (const float*)d_in[0];
  const float* w_q   = (const float*)d_in[2];
  const float* w_k   = (const float*)d_in[3];
  const float* w_v   = (const float*)d_in[4];
  const float* w_o   = (const float*)d_in[5];
  const float* subln = (const float*)d_in[6];

  char* ws = (char*)d_ws;
  u16*   wqq = (u16*)(ws + 0);                    // 33554432 B
  u16*   wqk = (u16*)(ws + 33554432L);            // 8388608
  u16*   wqv = (u16*)(ws + 41943040L);            // 8388608
  u16*   wqo = (u16*)(ws + 50331648L);            // 33554432
  u16*   xq  = (u16*)(ws + 83886080L);            // 16777216
  float* qf  = (float*)(ws + 100663296L);         // 33554432 (later: ao)
  float* kf  = (float*)(ws + 134217728L);         // 8388608  (later: yq lo)
  u16*   qb  = (u16*)(ws + 150994944L);           // 16777216
  u16*   kb  = (u16*)(ws + 167772160L);           // 4194304
  u16*   vtb = (u16*)(ws + 171966464L);           // 4194304
  float* cosb= (float*)(ws + 176160768L);         // 262144
  float* sinb= (float*)(ws + 176422912L);         // 262144
  float* xs  = (float*)(ws + 176685056L);         // 8192
  float* ys  = (float*)(ws + 176693248L);         // 8192
  float* wsc = (float*)(ws + 176701440L);         // 16
  float* par = (float*)(ws + 176701696L);         // 16384
  float* ao  = qf;
  u16*   yq  = (u16*)kf;
  float* out = (float*)d_out;

  // 1. weight scales
  k_abssum<<<1024, 256, 0, stream>>>(w_q, 16777216L/4, par + 0*1024);
  k_abssum<<<1024, 256, 0, stream>>>(w_k,  4194304L/4, par + 1*1024);
  k_abssum<<<1024, 256, 0, stream>>>(w_v,  4194304L/4, par + 2*1024);
  k_abssum<<<1024, 256, 0, stream>>>(w_o, 16777216L/4, par + 3*1024);
  k_wscale<<<1, 256, 0, stream>>>(par, wsc);

  // 2. quantize weights (ternary, bf16)
  k_quantw<<<16384, 256, 0, stream>>>(w_q, wqq, wsc, 0);
  k_quantw<<< 4096, 256, 0, stream>>>(w_k, wqk, wsc, 1);
  k_quantw<<< 4096, 256, 0, stream>>>(w_v, wqv, wsc, 2);
  k_quantw<<<16384, 256, 0, stream>>>(w_o, wqo, wsc, 3);

  // 3. act quant of hidden
  k_actq<<<NROWS, 256, 0, stream>>>(hs, xq, xs);

  // 4. Q GEMM + fused K/V GEMM (V written bf16-transposed, k_vt eliminated)
  k_gemm<<<dim3(32, 16), 256, 0, stream>>>(xq, wqq, qf, xs, wsc, 0, NROWS, 4096, 4096);
  k_gemm_kv<<<dim3(8, 16, 2), 256, 0, stream>>>(xq, wqk, wqv, kf, vtb, xs, wsc);

  // 5. rope tables + apply
  k_ropetab<<<256, 256, 0, stream>>>(cosb, sinb);
  k_rope<<<16384, 256, 0, stream>>>(qf, qb, cosb, sinb, NHQ,  (long)NB*SEQ*NHQ*64);
  k_rope<<< 4096, 256, 0, stream>>>(kf, kb, cosb, sinb, NKVH, (long)NB*SEQ*NKVH*64);

  // 6. attention (writes ao, aliases qf — qf dead after rope)
  k_attn<<<dim3(8, 32, 2), 256, 0, stream>>>(qb, kb, vtb, ao);

  // 7. rmsnorm + act quant (writes yq over kf — dead after rope)
  k_rmsq<<<NROWS, 256, 0, stream>>>(ao, subln, yq, ys);

  // 8. output GEMM
  k_gemm<<<dim3(32, 16), 256, 0, stream>>>(yq, wqo, out, ys, wsc, 3, NROWS, 4096, 4096);
}

// Round 3
// 320.767 us; speedup vs baseline: 2.4995x; 1.5563x over previous
//
#include <hip/hip_runtime.h>
#include <hip/hip_bf16.h>
#include <cstdint>

typedef unsigned short u16;
typedef __bf16 bf16x8 __attribute__((ext_vector_type(8)));
typedef float f32x4 __attribute__((ext_vector_type(4)));
typedef int i32x4 __attribute__((ext_vector_type(4)));

#define SEQ 1024
#define HID 4096
#define NHQ 32
#define NKVH 8
#define HDIM 128
#define NB 2
#define NROWS (NB*SEQ)

static __device__ __forceinline__ u16 f2bf(float x) {
  __hip_bfloat16 h = __float2bfloat16(x);
  return *reinterpret_cast<u16*>(&h);
}

static __device__ __forceinline__ void gload16(const void* g, void* l) {
  __builtin_amdgcn_global_load_lds((__attribute__((address_space(1))) void*)(void*)g,
                                   (__attribute__((address_space(3))) void*)l, 16, 0, 0);
}

static __device__ __forceinline__ int pack4i8(float a, float b, float c, float d,
                                              float s, float lo, float hi) {
  int x0 = (int)fminf(fmaxf(rintf(a*s), lo), hi);
  int x1 = (int)fminf(fmaxf(rintf(b*s), lo), hi);
  int x2 = (int)fminf(fmaxf(rintf(c*s), lo), hi);
  int x3 = (int)fminf(fmaxf(rintf(d*s), lo), hi);
  return (x0 & 255) | ((x1 & 255) << 8) | ((x2 & 255) << 16) | ((x3 & 255) << 24);
}

// ---------------- weight abs-sum (pass 1) ----------------
__global__ __launch_bounds__(256) void k_abssum(const float* __restrict__ w, long n4,
                                                float* __restrict__ partial) {
  float s = 0.f;
  long stride = (long)gridDim.x * 256;
  const float4* w4 = (const float4*)w;
  for (long j = (long)blockIdx.x*256 + threadIdx.x; j < n4; j += stride) {
    float4 v = w4[j];
    s += fabsf(v.x) + fabsf(v.y) + fabsf(v.z) + fabsf(v.w);
  }
  #pragma unroll
  for (int off = 1; off < 64; off <<= 1) s += __shfl_xor(s, off);
  __shared__ float red[4];
  if ((threadIdx.x & 63) == 0) red[threadIdx.x >> 6] = s;
  __syncthreads();
  if (threadIdx.x == 0) partial[blockIdx.x] = red[0] + red[1] + red[2] + red[3];
}

// ---------------- weight scales (pass 2) ----------------
__global__ __launch_bounds__(256) void k_wscale(const float* __restrict__ partial,
                                                float* __restrict__ wsc) {
  __shared__ float red[4];
  const float nelem[4] = {16777216.f, 4194304.f, 4194304.f, 16777216.f};
  for (int wi = 0; wi < 4; ++wi) {
    float s = 0.f;
    for (int j = threadIdx.x; j < 1024; j += 256) s += partial[wi*1024 + j];
    #pragma unroll
    for (int off = 1; off < 64; off <<= 1) s += __shfl_xor(s, off);
    if ((threadIdx.x & 63) == 0) red[threadIdx.x >> 6] = s;
    __syncthreads();
    if (threadIdx.x == 0) wsc[wi] = fmaxf((red[0]+red[1]+red[2]+red[3]) / nelem[wi], 1e-5f);
    __syncthreads();
  }
}

// ---------------- ternary weight quantize -> int8 ----------------
__global__ __launch_bounds__(256) void k_quantw8(const float* __restrict__ w, char* __restrict__ wq,
                                                 const float* __restrict__ wsc, int idx, int nchunk) {
  // nchunk = total float4 chunks / 256 per block; grid covers exactly
  long base = (long)blockIdx.x * 256 * 1 + threadIdx.x;   // one float4 per thread per iter
  (void)nchunk;
  float inv = 1.0f / wsc[idx];
  float4 v = ((const float4*)w)[base];
  ((int*)wq)[base] = pack4i8(v.x, v.y, v.z, v.w, inv, -1.f, 1.f);
}

// ---------------- per-row activation quantize (hidden) -> int8 ----------------
__global__ __launch_bounds__(256) void k_actq8(const float* __restrict__ x, char* __restrict__ xq,
                                               float* __restrict__ xs) {
  long row = blockIdx.x;
  const float4* xr = (const float4*)(x + row*HID);
  float4 v[4];
  float am = 0.f;
  #pragma unroll
  for (int j = 0; j < 4; ++j) {
    v[j] = xr[j*256 + threadIdx.x];
    am = fmaxf(am, fmaxf(fmaxf(fabsf(v[j].x), fabsf(v[j].y)), fmaxf(fabsf(v[j].z), fabsf(v[j].w))));
  }
  #pragma unroll
  for (int off = 1; off < 64; off <<= 1) am = fmaxf(am, __shfl_xor(am, off));
  __shared__ float red[4];
  if ((threadIdx.x & 63) == 0) red[threadIdx.x >> 6] = am;
  __syncthreads();
  am = fmaxf(fmaxf(red[0], red[1]), fmaxf(red[2], red[3]));
  float amc = fmaxf(am, 1e-5f);
  float s = 127.0f / amc;
  int* oq = (int*)(xq + row*HID);
  #pragma unroll
  for (int j = 0; j < 4; ++j)
    oq[j*256 + threadIdx.x] = pack4i8(v[j].x, v[j].y, v[j].z, v[j].w, s, -128.f, 127.f);
  if (threadIdx.x == 0) xs[row] = amc / 127.0f;
}

// ---------------- i8 GEMM: C[M][N] = A[M][K] * W[N][K]^T * arow[m] * wsc ----------------
__global__ __launch_bounds__(256) void k_gemm8(const char* __restrict__ A, const char* __restrict__ W,
                                               float* __restrict__ C, const float* __restrict__ arow,
                                               const float* __restrict__ wsc, int widx,
                                               int M, int N, int K) {
  __shared__ char As[128*64] __attribute__((aligned(16)));
  __shared__ char Ws_[128*64] __attribute__((aligned(16)));
  int t = threadIdx.x;
  int bm = blockIdx.y, bn = blockIdx.x;
  const char* Ab = A + (long)bm*128*K;
  const char* Wb = W + (long)bn*128*K;
  int lane = t & 63, wid = t >> 6;
  int wr = wid >> 1, wc = wid & 1;
  int lrow = lane & 15, l8 = lane >> 4;
  i32x4 zero = {0, 0, 0, 0};
  i32x4 acc[4][4];
  #pragma unroll
  for (int mi = 0; mi < 4; ++mi)
    #pragma unroll
    for (int ni = 0; ni < 4; ++ni) acc[mi][ni] = zero;

  int f0 = t, f1 = t + 256;
  int r0 = f0 >> 2, c0 = (f0 & 3) * 16;
  int r1 = f1 >> 2, c1 = (f1 & 3) * 16;
  int nk = K >> 6;
  for (int kt = 0; kt < nk; ++kt) {
    gload16(Ab + (long)r0*K + kt*64 + c0, &As[f0*16]);
    gload16(Ab + (long)r1*K + kt*64 + c1, &As[f1*16]);
    gload16(Wb + (long)r0*K + kt*64 + c0, &Ws_[f0*16]);
    gload16(Wb + (long)r1*K + kt*64 + c1, &Ws_[f1*16]);
    __syncthreads();
    i32x4 af[4], bfr[4];
    #pragma unroll
    for (int mi = 0; mi < 4; ++mi) af[mi] = *(const i32x4*)&As[(wr*64 + mi*16 + lrow)*64 + l8*16];
    #pragma unroll
    for (int ni = 0; ni < 4; ++ni) bfr[ni] = *(const i32x4*)&Ws_[(wc*64 + ni*16 + lrow)*64 + l8*16];
    #pragma unroll
    for (int mi = 0; mi < 4; ++mi)
      #pragma unroll
      for (int ni = 0; ni < 4; ++ni)
        acc[mi][ni] = __builtin_amdgcn_mfma_i32_16x16x64_i8(af[mi], bfr[ni], acc[mi][ni], 0, 0, 0);
    __syncthreads();
  }
  float ws = wsc[widx];
  #pragma unroll
  for (int mi = 0; mi < 4; ++mi)
    #pragma unroll
    for (int r = 0; r < 4; ++r) {
      int row = bm*128 + wr*64 + mi*16 + l8*4 + r;
      float sc = arow[row] * ws;
      #pragma unroll
      for (int ni = 0; ni < 4; ++ni) {
        int col = bn*128 + wc*64 + ni*16 + lrow;
        C[(long)row*N + col] = (float)acc[mi][ni][r] * sc;
      }
    }
}

// ---------------- merged i8 QKV GEMM (flat grid 768 blocks, 3/CU) ----------------
// bx<512: Q -> Cq fp32 [2048][4096]; bx<640: K -> Ck fp32 [2048][1024];
// else:   V -> Vt bf16 transposed [b][hkv][d][s]
__global__ __launch_bounds__(256) void k_gemm8_qkv(const char* __restrict__ A,
    const char* __restrict__ Wq, const char* __restrict__ Wk, const char* __restrict__ Wv,
    float* __restrict__ Cq, float* __restrict__ Ck, u16* __restrict__ Vt,
    const float* __restrict__ arow, const float* __restrict__ wsc) {
  const int K = 4096;
  int bx = blockIdx.x;
  int kind, bm, bn;
  const char* W;
  if (bx < 512)      { kind = 0; bm = bx >> 5;          bn = bx & 31; W = Wq; }
  else if (bx < 640) { kind = 1; bm = (bx - 512) >> 3;  bn = bx & 7;  W = Wk; }
  else               { kind = 2; bm = (bx - 640) >> 3;  bn = bx & 7;  W = Wv; }

  __shared__ char As[128*64] __attribute__((aligned(16)));
  __shared__ char Ws_[128*64] __attribute__((aligned(16)));
  int t = threadIdx.x;
  const char* Ab = A + (long)bm*128*K;
  const char* Wb = W + (long)bn*128*K;
  int lane = t & 63, wid = t >> 6;
  int wr = wid >> 1, wc = wid & 1;
  int lrow = lane & 15, l8 = lane >> 4;
  i32x4 zero = {0, 0, 0, 0};
  i32x4 acc[4][4];
  #pragma unroll
  for (int mi = 0; mi < 4; ++mi)
    #pragma unroll
    for (int ni = 0; ni < 4; ++ni) acc[mi][ni] = zero;

  int f0 = t, f1 = t + 256;
  int r0 = f0 >> 2, c0 = (f0 & 3) * 16;
  int r1 = f1 >> 2, c1 = (f1 & 3) * 16;
  for (int kt = 0; kt < (K >> 6); ++kt) {
    gload16(Ab + (long)r0*K + kt*64 + c0, &As[f0*16]);
    gload16(Ab + (long)r1*K + kt*64 + c1, &As[f1*16]);
    gload16(Wb + (long)r0*K + kt*64 + c0, &Ws_[f0*16]);
    gload16(Wb + (long)r1*K + kt*64 + c1, &Ws_[f1*16]);
    __syncthreads();
    i32x4 af[4], bfr[4];
    #pragma unroll
    for (int mi = 0; mi < 4; ++mi) af[mi] = *(const i32x4*)&As[(wr*64 + mi*16 + lrow)*64 + l8*16];
    #pragma unroll
    for (int ni = 0; ni < 4; ++ni) bfr[ni] = *(const i32x4*)&Ws_[(wc*64 + ni*16 + lrow)*64 + l8*16];
    #pragma unroll
    for (int mi = 0; mi < 4; ++mi)
      #pragma unroll
      for (int ni = 0; ni < 4; ++ni)
        acc[mi][ni] = __builtin_amdgcn_mfma_i32_16x16x64_i8(af[mi], bfr[ni], acc[mi][ni], 0, 0, 0);
    __syncthreads();
  }

  if (kind == 0) {
    float ws = wsc[0];
    #pragma unroll
    for (int mi = 0; mi < 4; ++mi)
      #pragma unroll
      for (int r = 0; r < 4; ++r) {
        int row = bm*128 + wr*64 + mi*16 + l8*4 + r;
        float sc = arow[row] * ws;
        #pragma unroll
        for (int ni = 0; ni < 4; ++ni) {
          int col = bn*128 + wc*64 + ni*16 + lrow;
          Cq[(long)row*4096 + col] = (float)acc[mi][ni][r] * sc;
        }
      }
  } else if (kind == 1) {
    float ws = wsc[1];
    #pragma unroll
    for (int mi = 0; mi < 4; ++mi)
      #pragma unroll
      for (int r = 0; r < 4; ++r) {
        int row = bm*128 + wr*64 + mi*16 + l8*4 + r;
        float sc = arow[row] * ws;
        #pragma unroll
        for (int ni = 0; ni < 4; ++ni) {
          int col = bn*128 + wc*64 + ni*16 + lrow;
          Ck[(long)row*1024 + col] = (float)acc[mi][ni][r] * sc;
        }
      }
  } else {
    float ws = wsc[2];
    #pragma unroll
    for (int mi = 0; mi < 4; ++mi) {
      int row0 = bm*128 + wr*64 + mi*16 + l8*4;
      int bidx = row0 >> 10, s0 = row0 & 1023;
      #pragma unroll
      for (int ni = 0; ni < 4; ++ni) {
        int col = bn*128 + wc*64 + ni*16 + lrow;
        int hkv = col >> 7, d = col & 127;
        ushort4 o4;
        o4.x = f2bf((float)acc[mi][ni][0] * arow[row0+0] * ws);
        o4.y = f2bf((float)acc[mi][ni][1] * arow[row0+1] * ws);
        o4.z = f2bf((float)acc[mi][ni][2] * arow[row0+2] * ws);
        o4.w = f2bf((float)acc[mi][ni][3] * arow[row0+3] * ws);
        *(ushort4*)&Vt[(((long)bidx*NKVH + hkv)*HDIM + d)*SEQ + s0] = o4;
      }
    }
  }
}

// ---------------- rope tables ----------------
__global__ __launch_bounds__(256) void k_ropetab(float* __restrict__ cosb, float* __restrict__ sinb) {
  int idx = blockIdx.x*256 + threadIdx.x;
  int s = idx >> 6, i = idx & 63;
  float e = (2.0f * (float)i) / 128.0f;
  float inv = 1.0f / powf(500000.0f, e);
  float f = (float)s * inv;
  cosb[idx] = cosf(f);
  sinb[idx] = sinf(f);
}

// ---------------- rope apply + layout to [b][h][s][d] bf16 ----------------
__global__ __launch_bounds__(256) void k_rope(const float* __restrict__ src, u16* __restrict__ dst,
                                              const float* __restrict__ cosb, const float* __restrict__ sinb,
                                              int nh, long total) {
  long idx = (long)blockIdx.x*256 + threadIdx.x;
  if (idx >= total) return;
  int i = (int)(idx & 63);
  long r1 = idx >> 6;
  int h = (int)(r1 % nh);
  long bs = r1 / nh;
  int s = (int)(bs & (SEQ-1));
  int b = (int)(bs >> 10);
  const float* p = src + bs*((long)nh*HDIM) + h*HDIM + 2*i;
  float a = p[0], bb = p[1];
  float c = cosb[(s<<6) + i], sn = sinb[(s<<6) + i];
  long o = (((long)b*nh + h)*SEQ + s)*HDIM + 2*i;
  dst[o]   = f2bf(a*c - bb*sn);
  dst[o+1] = f2bf(a*sn + bb*c);
}

// ---------------- causal GQA flash attention, LDS-staged, causal-paired ----------------
__global__ __launch_bounds__(256) void k_attn(const u16* __restrict__ qb, const u16* __restrict__ kb,
                                              const u16* __restrict__ vt, float* __restrict__ ao) {
  int p = blockIdx.x, h = blockIdx.y, b = blockIdx.z;
  int t = threadIdx.x, lane = t & 63, wid = t >> 6;
  int lrow = lane & 15, l8 = lane >> 4;
  int x7 = lrow & 7;

  __shared__ u16 Ks[2][64*128] __attribute__((aligned(16)));
  __shared__ u16 Vs[2][128*64] __attribute__((aligned(16)));
  __shared__ u16 Ps[4][16][72] __attribute__((aligned(16)));

  const u16* kp = kb + ((long)(b*NKVH + (h >> 2)))*SEQ*HDIM;
  const u16* vp = vt + ((long)(b*NKVH + (h >> 2)))*HDIM*SEQ;

  auto stageK = [&](int buf, int j) {
    const u16* src = kp + (long)j*64*HDIM;
    #pragma unroll
    for (int i = 0; i < 4; ++i) {
      int r0 = wid*16 + i*4;
      int row = r0 + (lane >> 4);
      int cg = (lane & 15) ^ (row & 7);
      gload16(src + (long)row*HDIM + cg*8, &Ks[buf][r0*HDIM]);
    }
  };
  auto stageV = [&](int buf, int j) {
    #pragma unroll
    for (int i = 0; i < 4; ++i) {
      int r0 = wid*32 + i*8;
      int row = r0 + (lane >> 3);
      int cg = (lane & 7) ^ (row & 7);
      gload16(vp + (long)row*SEQ + j*64 + cg*8, &Vs[buf][r0*64]);
    }
  };

  for (int phase = 0; phase < 2; ++phase) {
    int qt = phase ? (15 - p) : p;
    int q0 = qt*64 + wid*16;
    const u16* qp = qb + (((long)(b*NHQ + h))*SEQ + q0)*HDIM;
    bf16x8 qf[4];
    #pragma unroll
    for (int ks = 0; ks < 4; ++ks) qf[ks] = *(const bf16x8*)&qp[lrow*HDIM + ks*32 + l8*8];
    f32x4 zero = {0.f, 0.f, 0.f, 0.f};
    f32x4 o[8];
    #pragma unroll
    for (int f = 0; f < 8; ++f) o[f] = zero;
    float m[4], ll[4];
    #pragma unroll
    for (int r = 0; r < 4; ++r) { m[r] = -1e30f; ll[r] = 0.f; }

    int nj = qt + 1;
    stageK(0, 0); stageV(0, 0);
    __syncthreads();
    int cur = 0;
    for (int j = 0; j < nj; ++j) {
      if (j + 1 < nj) { stageK(cur ^ 1, j + 1); stageV(cur ^ 1, j + 1); }
      const u16* Kc = Ks[cur];
      const u16* Vc = Vs[cur];
      f32x4 sc4[4];
      #pragma unroll
      for (int ni = 0; ni < 4; ++ni) sc4[ni] = zero;
      __builtin_amdgcn_s_setprio(1);
      #pragma unroll
      for (int ni = 0; ni < 4; ++ni) {
        int row = ni*16 + lrow;
        #pragma unroll
        for (int ks = 0; ks < 4; ++ks) {
          int cl = (ks*4 + l8) ^ x7;
          bf16x8 kfr = *(const bf16x8*)&Kc[row*HDIM + cl*8];
          sc4[ni] = __builtin_amdgcn_mfma_f32_16x16x32_bf16(qf[ks], kfr, sc4[ni], 0, 0, 0);
        }
      }
      __builtin_amdgcn_s_setprio(0);
      const float scale = 0.08838834764831845f;
      float pm[4] = {-1e30f, -1e30f, -1e30f, -1e30f};
      float pv[4][4];
      bool diag = (j == qt);
      #pragma unroll
      for (int ni = 0; ni < 4; ++ni) {
        int kv = j*64 + ni*16 + lrow;
        #pragma unroll
        for (int r = 0; r < 4; ++r) {
          int qr = q0 + l8*4 + r;
          float val = sc4[ni][r] * scale;
          if (diag && kv > qr) val = -1e30f;
          pv[ni][r] = val;
          pm[r] = fmaxf(pm[r], val);
        }
      }
      #pragma unroll
      for (int r = 0; r < 4; ++r) {
        #pragma unroll
        for (int off = 1; off < 16; off <<= 1) pm[r] = fmaxf(pm[r], __shfl_xor(pm[r], off));
      }
      float fr[4], rs[4];
      #pragma unroll
      for (int r = 0; r < 4; ++r) {
        float nm = fmaxf(m[r], pm[r]);
        fr[r] = __expf(m[r] - nm);
        m[r] = nm; rs[r] = 0.f;
      }
      #pragma unroll
      for (int ni = 0; ni < 4; ++ni)
        #pragma unroll
        for (int r = 0; r < 4; ++r) {
          float pe = __expf(pv[ni][r] - m[r]);
          pv[ni][r] = pe; rs[r] += pe;
        }
      #pragma unroll
      for (int r = 0; r < 4; ++r) {
        #pragma unroll
        for (int off = 1; off < 16; off <<= 1) rs[r] += __shfl_xor(rs[r], off);
        ll[r] = ll[r]*fr[r] + rs[r];
      }
      #pragma unroll
      for (int f = 0; f < 8; ++f) {
        o[f][0] *= fr[0]; o[f][1] *= fr[1]; o[f][2] *= fr[2]; o[f][3] *= fr[3];
      }
      #pragma unroll
      for (int ni = 0; ni < 4; ++ni)
        #pragma unroll
        for (int r = 0; r < 4; ++r)
          Ps[wid][l8*4 + r][ni*16 + lrow] = f2bf(pv[ni][r]);
      bf16x8 pf0 = *(const bf16x8*)&Ps[wid][lrow][l8*8];
      bf16x8 pf1 = *(const bf16x8*)&Ps[wid][lrow][32 + l8*8];
      __builtin_amdgcn_s_setprio(1);
      #pragma unroll
      for (int f = 0; f < 8; ++f) {
        int d = f*16 + lrow;
        bf16x8 v0 = *(const bf16x8*)&Vc[d*64 + ((l8) ^ x7)*8];
        bf16x8 v1 = *(const bf16x8*)&Vc[d*64 + ((4 + l8) ^ x7)*8];
        o[f] = __builtin_amdgcn_mfma_f32_16x16x32_bf16(pf0, v0, o[f], 0, 0, 0);
        o[f] = __builtin_amdgcn_mfma_f32_16x16x32_bf16(pf1, v1, o[f], 0, 0, 0);
      }
      __builtin_amdgcn_s_setprio(0);
      __syncthreads();
      cur ^= 1;
    }
    float invl[4];
    #pragma unroll
    for (int r = 0; r < 4; ++r) invl[r] = 1.0f / ll[r];
    #pragma unroll
    for (int f = 0; f < 8; ++f)
      #pragma unroll
      for (int r = 0; r < 4; ++r) {
        long row = (long)b*SEQ + q0 + l8*4 + r;
        ao[row*HID + h*HDIM + f*16 + lrow] = o[f][r] * invl[r];
      }
    __syncthreads();
  }
}

// ---------------- fused rmsnorm + act quant -> int8 ----------------
__global__ __launch_bounds__(256) void k_rmsq8(const float* __restrict__ x, const float* __restrict__ w,
                                               char* __restrict__ yq, float* __restrict__ ys) {
  long row = blockIdx.x;
  const float4* xr = (const float4*)(x + row*HID);
  const float4* wr = (const float4*)w;
  float4 v[4];
  float ss = 0.f;
  #pragma unroll
  for (int j = 0; j < 4; ++j) {
    v[j] = xr[j*256 + threadIdx.x];
    ss += v[j].x*v[j].x + v[j].y*v[j].y + v[j].z*v[j].z + v[j].w*v[j].w;
  }
  #pragma unroll
  for (int off = 1; off < 64; off <<= 1) ss += __shfl_xor(ss, off);
  __shared__ float red[4];
  if ((threadIdx.x & 63) == 0) red[threadIdx.x >> 6] = ss;
  __syncthreads();
  ss = red[0] + red[1] + red[2] + red[3];
  __syncthreads();
  float rn = rsqrtf(ss / (float)HID + 1e-6f);
  float4 y[4];
  float am = 0.f;
  #pragma unroll
  for (int j = 0; j < 4; ++j) {
    float4 wv = wr[j*256 + threadIdx.x];
    y[j].x = v[j].x * rn * wv.x; y[j].y = v[j].y * rn * wv.y;
    y[j].z = v[j].z * rn * wv.z; y[j].w = v[j].w * rn * wv.w;
    am = fmaxf(am, fmaxf(fmaxf(fabsf(y[j].x), fabsf(y[j].y)), fmaxf(fabsf(y[j].z), fabsf(y[j].w))));
  }
  #pragma unroll
  for (int off = 1; off < 64; off <<= 1) am = fmaxf(am, __shfl_xor(am, off));
  if ((threadIdx.x & 63) == 0) red[threadIdx.x >> 6] = am;
  __syncthreads();
  am = fmaxf(fmaxf(red[0], red[1]), fmaxf(red[2], red[3]));
  float amc = fmaxf(am, 1e-5f);
  float s = 127.0f / amc;
  int* oq = (int*)(yq + row*HID);
  #pragma unroll
  for (int j = 0; j < 4; ++j)
    oq[j*256 + threadIdx.x] = pack4i8(y[j].x, y[j].y, y[j].z, y[j].w, s, -128.f, 127.f);
  if (threadIdx.x == 0) ys[row] = amc / 127.0f;
}

extern "C" void kernel_launch(void* const* d_in, const int* in_sizes, int n_in,
                              void* d_out, int out_size, void* d_ws, size_t ws_size,
                              hipStream_t stream) {
  const float* hs    = (const float*)d_in[0];
  const float* w_q   = (const float*)d_in[2];
  const float* w_k   = (const float*)d_in[3];
  const float* w_v   = (const float*)d_in[4];
  const float* w_o   = (const float*)d_in[5];
  const float* subln = (const float*)d_in[6];

  char* ws = (char*)d_ws;
  char*  wqq = (char*)(ws + 0L);                  // 16777216 (i8)
  char*  wqk = (char*)(ws + 16777216L);           // 4194304
  char*  wqv = (char*)(ws + 20971520L);           // 4194304
  char*  wqo = (char*)(ws + 25165824L);           // 16777216
  char*  xq  = (char*)(ws + 41943040L);           // 8388608
  float* qf  = (float*)(ws + 50331648L);          // 33554432 (fp32 Q out; later ao)
  float* kf  = (float*)(ws + 83886080L);          // 8388608  (fp32 K out; later yq i8)
  u16*   qb  = (u16*)(ws + 92274688L);            // 16777216
  u16*   kb  = (u16*)(ws + 109051904L);           // 4194304
  u16*   vtb = (u16*)(ws + 113246208L);           // 4194304
  float* cosb= (float*)(ws + 117440512L);         // 262144
  float* sinb= (float*)(ws + 117702656L);         // 262144
  float* xs  = (float*)(ws + 117964800L);         // 8192
  float* ys  = (float*)(ws + 117972992L);         // 8192
  float* wsc = (float*)(ws + 117981184L);         // 64
  float* par = (float*)(ws + 117981248L);         // 16384
  float* ao  = qf;
  char*  yq  = (char*)kf;
  float* out = (float*)d_out;

  // 1. weight scales
  k_abssum<<<1024, 256, 0, stream>>>(w_q, 16777216L/4, par + 0*1024);
  k_abssum<<<1024, 256, 0, stream>>>(w_k,  4194304L/4, par + 1*1024);
  k_abssum<<<1024, 256, 0, stream>>>(w_v,  4194304L/4, par + 2*1024);
  k_abssum<<<1024, 256, 0, stream>>>(w_o, 16777216L/4, par + 3*1024);
  k_wscale<<<1, 256, 0, stream>>>(par, wsc);

  // 2. quantize weights (ternary, int8)
  k_quantw8<<<16384, 256, 0, stream>>>(w_q, wqq, wsc, 0, 0);
  k_quantw8<<< 4096, 256, 0, stream>>>(w_k, wqk, wsc, 1, 0);
  k_quantw8<<< 4096, 256, 0, stream>>>(w_v, wqv, wsc, 2, 0);
  k_quantw8<<<16384, 256, 0, stream>>>(w_o, wqo, wsc, 3, 0);

  // 3. act quant of hidden (int8)
  k_actq8<<<NROWS, 256, 0, stream>>>(hs, xq, xs);

  // 4. merged Q/K/V i8 GEMM (768 blocks -> 3/CU); V written bf16-transposed
  k_gemm8_qkv<<<768, 256, 0, stream>>>(xq, wqq, wqk, wqv, qf, kf, vtb, xs, wsc);

  // 5. rope tables + apply
  k_ropetab<<<256, 256, 0, stream>>>(cosb, sinb);
  k_rope<<<16384, 256, 0, stream>>>(qf, qb, cosb, sinb, NHQ,  (long)NB*SEQ*NHQ*64);
  k_rope<<< 4096, 256, 0, stream>>>(kf, kb, cosb, sinb, NKVH, (long)NB*SEQ*NKVH*64);

  // 6. attention (writes ao, aliases qf — qf dead after rope)
  k_attn<<<dim3(8, 32, 2), 256, 0, stream>>>(qb, kb, vtb, ao);

  // 7. rmsnorm + act quant (writes yq over kf — dead after rope)
  k_rmsq8<<<NROWS, 256, 0, stream>>>(ao, subln, yq, ys);

  // 8. output i8 GEMM
  k_gemm8<<<dim3(32, 16), 256, 0, stream>>>(yq, wqo, out, ys, wsc, 3, NROWS, 4096, 4096);
}

// Round 4
// 302.566 us; speedup vs baseline: 2.6499x; 1.0602x over previous
//
#include <hip/hip_runtime.h>
#include <hip/hip_bf16.h>
#include <cstdint>

typedef unsigned short u16;
typedef __bf16 bf16x8 __attribute__((ext_vector_type(8)));
typedef float f32x4 __attribute__((ext_vector_type(4)));
typedef int i32x4 __attribute__((ext_vector_type(4)));

#define SEQ 1024
#define HID 4096
#define NHQ 32
#define NKVH 8
#define HDIM 128
#define NB 2
#define NROWS (NB*SEQ)

static __device__ __forceinline__ u16 f2bf(float x) {
  __hip_bfloat16 h = __float2bfloat16(x);
  return *reinterpret_cast<u16*>(&h);
}

static __device__ __forceinline__ void gload16(const void* g, void* l) {
  __builtin_amdgcn_global_load_lds((__attribute__((address_space(1))) void*)(void*)g,
                                   (__attribute__((address_space(3))) void*)l, 16, 0, 0);
}

static __device__ __forceinline__ int pack4i8(float a, float b, float c, float d,
                                              float s, float lo, float hi) {
  int x0 = (int)fminf(fmaxf(rintf(a*s), lo), hi);
  int x1 = (int)fminf(fmaxf(rintf(b*s), lo), hi);
  int x2 = (int)fminf(fmaxf(rintf(c*s), lo), hi);
  int x3 = (int)fminf(fmaxf(rintf(d*s), lo), hi);
  return (x0 & 255) | ((x1 & 255) << 8) | ((x2 & 255) << 16) | ((x3 & 255) << 24);
}

// ---------------- merged weight abs-sum (pass 1): 2560 blocks ----------------
__global__ __launch_bounds__(256) void k_abssum4(const float* __restrict__ wq_, const float* __restrict__ wk_,
                                                 const float* __restrict__ wv_, const float* __restrict__ wo_,
                                                 float* __restrict__ partial) {
  int bx = blockIdx.x;
  const float* w; long n4; int pbase, lb, nb;
  if (bx < 1024)      { w = wq_; n4 = 4194304; pbase = 0;    lb = bx;        nb = 1024; }
  else if (bx < 1280) { w = wk_; n4 = 1048576; pbase = 1024; lb = bx - 1024; nb = 256; }
  else if (bx < 1536) { w = wv_; n4 = 1048576; pbase = 1280; lb = bx - 1280; nb = 256; }
  else                { w = wo_; n4 = 4194304; pbase = 1536; lb = bx - 1536; nb = 1024; }
  float s = 0.f;
  long stride = (long)nb * 256;
  const float4* w4 = (const float4*)w;
  for (long j = (long)lb*256 + threadIdx.x; j < n4; j += stride) {
    float4 v = w4[j];
    s += fabsf(v.x) + fabsf(v.y) + fabsf(v.z) + fabsf(v.w);
  }
  #pragma unroll
  for (int off = 1; off < 64; off <<= 1) s += __shfl_xor(s, off);
  __shared__ float red[4];
  if ((threadIdx.x & 63) == 0) red[threadIdx.x >> 6] = s;
  __syncthreads();
  if (threadIdx.x == 0) partial[pbase + lb] = red[0] + red[1] + red[2] + red[3];
}

// ---------------- weight scales (pass 2) ----------------
__global__ __launch_bounds__(256) void k_wscale(const float* __restrict__ partial,
                                                float* __restrict__ wsc) {
  __shared__ float red[4];
  const float nelem[4] = {16777216.f, 4194304.f, 4194304.f, 16777216.f};
  const int pbase[4] = {0, 1024, 1280, 1536};
  const int pcnt[4]  = {1024, 256, 256, 1024};
  for (int wi = 0; wi < 4; ++wi) {
    float s = 0.f;
    for (int j = threadIdx.x; j < pcnt[wi]; j += 256) s += partial[pbase[wi] + j];
    #pragma unroll
    for (int off = 1; off < 64; off <<= 1) s += __shfl_xor(s, off);
    if ((threadIdx.x & 63) == 0) red[threadIdx.x >> 6] = s;
    __syncthreads();
    if (threadIdx.x == 0) wsc[wi] = fmaxf((red[0]+red[1]+red[2]+red[3]) / nelem[wi], 1e-5f);
    __syncthreads();
  }
}

// ---------------- merged ternary weight quantize -> int8 (40960 blocks) ----------------
__global__ __launch_bounds__(256) void k_quantw8_all(const float* __restrict__ wq_, const float* __restrict__ wk_,
                                                     const float* __restrict__ wv_, const float* __restrict__ wo_,
                                                     char* __restrict__ oq_, char* __restrict__ ok_,
                                                     char* __restrict__ ov_, char* __restrict__ oo_,
                                                     const float* __restrict__ wsc) {
  int bx = blockIdx.x;
  const float* src; char* dst; int idx; long base;
  if (bx < 16384)      { src = wq_; dst = oq_; idx = 0; base = bx; }
  else if (bx < 20480) { src = wk_; dst = ok_; idx = 1; base = bx - 16384; }
  else if (bx < 24576) { src = wv_; dst = ov_; idx = 2; base = bx - 20480; }
  else                 { src = wo_; dst = oo_; idx = 3; base = bx - 24576; }
  long j = base*256 + threadIdx.x;
  float inv = 1.0f / wsc[idx];
  float4 v = ((const float4*)src)[j];
  ((int*)dst)[j] = pack4i8(v.x, v.y, v.z, v.w, inv, -1.f, 1.f);
}

// ---------------- per-row activation quantize (hidden) -> int8 ----------------
__global__ __launch_bounds__(256) void k_actq8(const float* __restrict__ x, char* __restrict__ xq,
                                               float* __restrict__ xs) {
  long row = blockIdx.x;
  const float4* xr = (const float4*)(x + row*HID);
  float4 v[4];
  float am = 0.f;
  #pragma unroll
  for (int j = 0; j < 4; ++j) {
    v[j] = xr[j*256 + threadIdx.x];
    am = fmaxf(am, fmaxf(fmaxf(fabsf(v[j].x), fabsf(v[j].y)), fmaxf(fabsf(v[j].z), fabsf(v[j].w))));
  }
  #pragma unroll
  for (int off = 1; off < 64; off <<= 1) am = fmaxf(am, __shfl_xor(am, off));
  __shared__ float red[4];
  if ((threadIdx.x & 63) == 0) red[threadIdx.x >> 6] = am;
  __syncthreads();
  am = fmaxf(fmaxf(red[0], red[1]), fmaxf(red[2], red[3]));
  float amc = fmaxf(am, 1e-5f);
  float s = 127.0f / amc;
  int* oq = (int*)(xq + row*HID);
  #pragma unroll
  for (int j = 0; j < 4; ++j)
    oq[j*256 + threadIdx.x] = pack4i8(v[j].x, v[j].y, v[j].z, v[j].w, s, -128.f, 127.f);
  if (threadIdx.x == 0) xs[row] = amc / 127.0f;
}

// ---------------- i8 GEMM (O proj): C[M][N] = A*W^T * arow * wsc ----------------
// LDS chunk-XOR swizzle: physical chunk p = ci ^ ((row>>1)&3); staged via pre-swizzled
// global source (rule #21), read with lane-constant xsw = (lrow>>1)&3.
__global__ __launch_bounds__(256) void k_gemm8(const char* __restrict__ A, const char* __restrict__ W,
                                               float* __restrict__ C, const float* __restrict__ arow,
                                               const float* __restrict__ wsc, int widx,
                                               int M, int N, int K) {
  __shared__ char As[128*64] __attribute__((aligned(16)));
  __shared__ char Ws_[128*64] __attribute__((aligned(16)));
  int t = threadIdx.x;
  int bm = blockIdx.y, bn = blockIdx.x;
  const char* Ab = A + (long)bm*128*K;
  const char* Wb = W + (long)bn*128*K;
  int lane = t & 63, wid = t >> 6;
  int wr = wid >> 1, wc = wid & 1;
  int lrow = lane & 15, l8 = lane >> 4;
  int xsw = (lrow >> 1) & 3;
  int ch0 = (l8 ^ xsw) * 16;
  i32x4 zero = {0, 0, 0, 0};
  i32x4 acc[4][4];
  #pragma unroll
  for (int mi = 0; mi < 4; ++mi)
    #pragma unroll
    for (int ni = 0; ni < 4; ++ni) acc[mi][ni] = zero;

  int f0 = t, f1 = t + 256;
  int r0 = f0 >> 2, c0 = ((f0 & 3) ^ ((f0 >> 3) & 3)) * 16;
  int r1 = f1 >> 2, c1 = ((f1 & 3) ^ ((f1 >> 3) & 3)) * 16;
  int nk = K >> 6;
  for (int kt = 0; kt < nk; ++kt) {
    gload16(Ab + (long)r0*K + kt*64 + c0, &As[f0*16]);
    gload16(Ab + (long)r1*K + kt*64 + c1, &As[f1*16]);
    gload16(Wb + (long)r0*K + kt*64 + c0, &Ws_[f0*16]);
    gload16(Wb + (long)r1*K + kt*64 + c1, &Ws_[f1*16]);
    __syncthreads();
    i32x4 af[4], bfr[4];
    #pragma unroll
    for (int mi = 0; mi < 4; ++mi) af[mi] = *(const i32x4*)&As[(wr*64 + mi*16 + lrow)*64 + ch0];
    #pragma unroll
    for (int ni = 0; ni < 4; ++ni) bfr[ni] = *(const i32x4*)&Ws_[(wc*64 + ni*16 + lrow)*64 + ch0];
    #pragma unroll
    for (int mi = 0; mi < 4; ++mi)
      #pragma unroll
      for (int ni = 0; ni < 4; ++ni)
        acc[mi][ni] = __builtin_amdgcn_mfma_i32_16x16x64_i8(af[mi], bfr[ni], acc[mi][ni], 0, 0, 0);
    __syncthreads();
  }
  float ws = wsc[widx];
  #pragma unroll
  for (int mi = 0; mi < 4; ++mi)
    #pragma unroll
    for (int r = 0; r < 4; ++r) {
      int row = bm*128 + wr*64 + mi*16 + l8*4 + r;
      float sc = arow[row] * ws;
      #pragma unroll
      for (int ni = 0; ni < 4; ++ni) {
        int col = bn*128 + wc*64 + ni*16 + lrow;
        C[(long)row*N + col] = (float)acc[mi][ni][r] * sc;
      }
    }
}

// ---------------- merged i8 QKV GEMM with fused RoPE epilogue (768 blocks) ----------------
// bx<512: Q -> Qb bf16 [b][32][s][d] (RoPE'd); bx<640: K -> Kb bf16 [b][8][s][d] (RoPE'd);
// else:   V -> Vt bf16 transposed [b][8][d][s]
__global__ __launch_bounds__(256) void k_gemm8_qkv(const char* __restrict__ A,
    const char* __restrict__ Wq, const char* __restrict__ Wk, const char* __restrict__ Wv,
    u16* __restrict__ Qb, u16* __restrict__ Kb, u16* __restrict__ Vt,
    const float* __restrict__ arow, const float* __restrict__ wsc,
    const float* __restrict__ cosb, const float* __restrict__ sinb) {
  const int K = 4096;
  int bx = blockIdx.x;
  int kind, bm, bn;
  const char* W;
  if (bx < 512)      { kind = 0; bm = bx >> 5;          bn = bx & 31; W = Wq; }
  else if (bx < 640) { kind = 1; bm = (bx - 512) >> 3;  bn = bx & 7;  W = Wk; }
  else               { kind = 2; bm = (bx - 640) >> 3;  bn = bx & 7;  W = Wv; }

  __shared__ char As[128*64] __attribute__((aligned(16)));
  __shared__ char Ws_[128*64] __attribute__((aligned(16)));
  int t = threadIdx.x;
  const char* Ab = A + (long)bm*128*K;
  const char* Wb = W + (long)bn*128*K;
  int lane = t & 63, wid = t >> 6;
  int wr = wid >> 1, wc = wid & 1;
  int lrow = lane & 15, l8 = lane >> 4;
  int xsw = (lrow >> 1) & 3;
  int ch0 = (l8 ^ xsw) * 16;
  i32x4 zero = {0, 0, 0, 0};
  i32x4 acc[4][4];
  #pragma unroll
  for (int mi = 0; mi < 4; ++mi)
    #pragma unroll
    for (int ni = 0; ni < 4; ++ni) acc[mi][ni] = zero;

  int f0 = t, f1 = t + 256;
  int r0 = f0 >> 2, c0 = ((f0 & 3) ^ ((f0 >> 3) & 3)) * 16;
  int r1 = f1 >> 2, c1 = ((f1 & 3) ^ ((f1 >> 3) & 3)) * 16;
  for (int kt = 0; kt < (K >> 6); ++kt) {
    gload16(Ab + (long)r0*K + kt*64 + c0, &As[f0*16]);
    gload16(Ab + (long)r1*K + kt*64 + c1, &As[f1*16]);
    gload16(Wb + (long)r0*K + kt*64 + c0, &Ws_[f0*16]);
    gload16(Wb + (long)r1*K + kt*64 + c1, &Ws_[f1*16]);
    __syncthreads();
    i32x4 af[4], bfr[4];
    #pragma unroll
    for (int mi = 0; mi < 4; ++mi) af[mi] = *(const i32x4*)&As[(wr*64 + mi*16 + lrow)*64 + ch0];
    #pragma unroll
    for (int ni = 0; ni < 4; ++ni) bfr[ni] = *(const i32x4*)&Ws_[(wc*64 + ni*16 + lrow)*64 + ch0];
    #pragma unroll
    for (int mi = 0; mi < 4; ++mi)
      #pragma unroll
      for (int ni = 0; ni < 4; ++ni)
        acc[mi][ni] = __builtin_amdgcn_mfma_i32_16x16x64_i8(af[mi], bfr[ni], acc[mi][ni], 0, 0, 0);
    __syncthreads();
  }

  if (kind == 2) {
    float ws = wsc[2];
    #pragma unroll
    for (int mi = 0; mi < 4; ++mi) {
      int row0 = bm*128 + wr*64 + mi*16 + l8*4;
      int bidx = row0 >> 10, s0 = row0 & 1023;
      #pragma unroll
      for (int ni = 0; ni < 4; ++ni) {
        int col = bn*128 + wc*64 + ni*16 + lrow;
        int hkv = col >> 7, d = col & 127;
        ushort4 o4;
        o4.x = f2bf((float)acc[mi][ni][0] * arow[row0+0] * ws);
        o4.y = f2bf((float)acc[mi][ni][1] * arow[row0+1] * ws);
        o4.z = f2bf((float)acc[mi][ni][2] * arow[row0+2] * ws);
        o4.w = f2bf((float)acc[mi][ni][3] * arow[row0+3] * ws);
        *(ushort4*)&Vt[(((long)bidx*NKVH + hkv)*HDIM + d)*SEQ + s0] = o4;
      }
    }
  } else {
    float ws = wsc[kind];
    u16* dst = kind ? Kb : Qb;
    int nh = kind ? NKVH : NHQ;
    #pragma unroll
    for (int mi = 0; mi < 4; ++mi) {
      #pragma unroll
      for (int r = 0; r < 4; ++r) {
        int row = bm*128 + wr*64 + mi*16 + l8*4 + r;
        int bidx = row >> 10, s = row & 1023;
        float sc = arow[row] * ws;
        #pragma unroll
        for (int ni = 0; ni < 4; ++ni) {
          int col = bn*128 + wc*64 + ni*16 + lrow;
          float val = (float)acc[mi][ni][r] * sc;
          float pv = __shfl_xor(val, 1);          // partner holds col^1 (RoPE pair)
          if (!(col & 1)) {
            int h = col >> 7, d = col & 127, i = d >> 1;
            float cc = cosb[(s << 6) + i], sn = sinb[(s << 6) + i];
            ushort2 o2;
            o2.x = f2bf(val*cc - pv*sn);
            o2.y = f2bf(val*sn + pv*cc);
            *(ushort2*)&dst[(((long)bidx*nh + h)*SEQ + s)*HDIM + d] = o2;
          }
        }
      }
    }
  }
}

// ---------------- rope tables ----------------
__global__ __launch_bounds__(256) void k_ropetab(float* __restrict__ cosb, float* __restrict__ sinb) {
  int idx = blockIdx.x*256 + threadIdx.x;
  int s = idx >> 6, i = idx & 63;
  float e = (2.0f * (float)i) / 128.0f;
  float inv = 1.0f / powf(500000.0f, e);
  float f = (float)s * inv;
  cosb[idx] = cosf(f);
  sinb[idx] = sinf(f);
}

// ---------------- causal GQA flash attention, LDS-staged, causal-paired ----------------
__global__ __launch_bounds__(256) void k_attn(const u16* __restrict__ qb, const u16* __restrict__ kb,
                                              const u16* __restrict__ vt, float* __restrict__ ao) {
  int p = blockIdx.x, h = blockIdx.y, b = blockIdx.z;
  int t = threadIdx.x, lane = t & 63, wid = t >> 6;
  int lrow = lane & 15, l8 = lane >> 4;
  int x7 = lrow & 7;

  __shared__ u16 Ks[2][64*128] __attribute__((aligned(16)));
  __shared__ u16 Vs[2][128*64] __attribute__((aligned(16)));
  __shared__ u16 Ps[4][16][72] __attribute__((aligned(16)));

  const u16* kp = kb + ((long)(b*NKVH + (h >> 2)))*SEQ*HDIM;
  const u16* vp = vt + ((long)(b*NKVH + (h >> 2)))*HDIM*SEQ;

  auto stageK = [&](int buf, int j) {
    const u16* src = kp + (long)j*64*HDIM;
    #pragma unroll
    for (int i = 0; i < 4; ++i) {
      int r0 = wid*16 + i*4;
      int row = r0 + (lane >> 4);
      int cg = (lane & 15) ^ (row & 7);
      gload16(src + (long)row*HDIM + cg*8, &Ks[buf][r0*HDIM]);
    }
  };
  auto stageV = [&](int buf, int j) {
    #pragma unroll
    for (int i = 0; i < 4; ++i) {
      int r0 = wid*32 + i*8;
      int row = r0 + (lane >> 3);
      int cg = (lane & 7) ^ (row & 7);
      gload16(vp + (long)row*SEQ + j*64 + cg*8, &Vs[buf][r0*64]);
    }
  };

  for (int phase = 0; phase < 2; ++phase) {
    int qt = phase ? (15 - p) : p;
    int q0 = qt*64 + wid*16;
    const u16* qp = qb + (((long)(b*NHQ + h))*SEQ + q0)*HDIM;
    bf16x8 qf[4];
    #pragma unroll
    for (int ks = 0; ks < 4; ++ks) qf[ks] = *(const bf16x8*)&qp[lrow*HDIM + ks*32 + l8*8];
    f32x4 zero = {0.f, 0.f, 0.f, 0.f};
    f32x4 o[8];
    #pragma unroll
    for (int f = 0; f < 8; ++f) o[f] = zero;
    float m[4], ll[4];
    #pragma unroll
    for (int r = 0; r < 4; ++r) { m[r] = -1e30f; ll[r] = 0.f; }

    int nj = qt + 1;
    stageK(0, 0); stageV(0, 0);
    __syncthreads();
    int cur = 0;
    for (int j = 0; j < nj; ++j) {
      if (j + 1 < nj) { stageK(cur ^ 1, j + 1); stageV(cur ^ 1, j + 1); }
      const u16* Kc = Ks[cur];
      const u16* Vc = Vs[cur];
      f32x4 sc4[4];
      #pragma unroll
      for (int ni = 0; ni < 4; ++ni) sc4[ni] = zero;
      __builtin_amdgcn_s_setprio(1);
      #pragma unroll
      for (int ni = 0; ni < 4; ++ni) {
        int row = ni*16 + lrow;
        #pragma unroll
        for (int ks = 0; ks < 4; ++ks) {
          int cl = (ks*4 + l8) ^ x7;
          bf16x8 kfr = *(const bf16x8*)&Kc[row*HDIM + cl*8];
          sc4[ni] = __builtin_amdgcn_mfma_f32_16x16x32_bf16(qf[ks], kfr, sc4[ni], 0, 0, 0);
        }
      }
      __builtin_amdgcn_s_setprio(0);
      const float scale = 0.08838834764831845f;
      float pm[4] = {-1e30f, -1e30f, -1e30f, -1e30f};
      float pv[4][4];
      bool diag = (j == qt);
      #pragma unroll
      for (int ni = 0; ni < 4; ++ni) {
        int kv = j*64 + ni*16 + lrow;
        #pragma unroll
        for (int r = 0; r < 4; ++r) {
          int qr = q0 + l8*4 + r;
          float val = sc4[ni][r] * scale;
          if (diag && kv > qr) val = -1e30f;
          pv[ni][r] = val;
          pm[r] = fmaxf(pm[r], val);
        }
      }
      #pragma unroll
      for (int r = 0; r < 4; ++r) {
        #pragma unroll
        for (int off = 1; off < 16; off <<= 1) pm[r] = fmaxf(pm[r], __shfl_xor(pm[r], off));
      }
      float fr[4], rs[4];
      #pragma unroll
      for (int r = 0; r < 4; ++r) {
        float nm = fmaxf(m[r], pm[r]);
        fr[r] = __expf(m[r] - nm);
        m[r] = nm; rs[r] = 0.f;
      }
      #pragma unroll
      for (int ni = 0; ni < 4; ++ni)
        #pragma unroll
        for (int r = 0; r < 4; ++r) {
          float pe = __expf(pv[ni][r] - m[r]);
          pv[ni][r] = pe; rs[r] += pe;
        }
      #pragma unroll
      for (int r = 0; r < 4; ++r) {
        #pragma unroll
        for (int off = 1; off < 16; off <<= 1) rs[r] += __shfl_xor(rs[r], off);
        ll[r] = ll[r]*fr[r] + rs[r];
      }
      #pragma unroll
      for (int f = 0; f < 8; ++f) {
        o[f][0] *= fr[0]; o[f][1] *= fr[1]; o[f][2] *= fr[2]; o[f][3] *= fr[3];
      }
      #pragma unroll
      for (int ni = 0; ni < 4; ++ni)
        #pragma unroll
        for (int r = 0; r < 4; ++r)
          Ps[wid][l8*4 + r][ni*16 + lrow] = f2bf(pv[ni][r]);
      bf16x8 pf0 = *(const bf16x8*)&Ps[wid][lrow][l8*8];
      bf16x8 pf1 = *(const bf16x8*)&Ps[wid][lrow][32 + l8*8];
      __builtin_amdgcn_s_setprio(1);
      #pragma unroll
      for (int f = 0; f < 8; ++f) {
        int d = f*16 + lrow;
        bf16x8 v0 = *(const bf16x8*)&Vc[d*64 + ((l8) ^ x7)*8];
        bf16x8 v1 = *(const bf16x8*)&Vc[d*64 + ((4 + l8) ^ x7)*8];
        o[f] = __builtin_amdgcn_mfma_f32_16x16x32_bf16(pf0, v0, o[f], 0, 0, 0);
        o[f] = __builtin_amdgcn_mfma_f32_16x16x32_bf16(pf1, v1, o[f], 0, 0, 0);
      }
      __builtin_amdgcn_s_setprio(0);
      __syncthreads();
      cur ^= 1;
    }
    float invl[4];
    #pragma unroll
    for (int r = 0; r < 4; ++r) invl[r] = 1.0f / ll[r];
    #pragma unroll
    for (int f = 0; f < 8; ++f)
      #pragma unroll
      for (int r = 0; r < 4; ++r) {
        long row = (long)b*SEQ + q0 + l8*4 + r;
        ao[row*HID + h*HDIM + f*16 + lrow] = o[f][r] * invl[r];
      }
    __syncthreads();
  }
}

// ---------------- fused rmsnorm + act quant -> int8 ----------------
__global__ __launch_bounds__(256) void k_rmsq8(const float* __restrict__ x, const float* __restrict__ w,
                                               char* __restrict__ yq, float* __restrict__ ys) {
  long row = blockIdx.x;
  const float4* xr = (const float4*)(x + row*HID);
  const float4* wr = (const float4*)w;
  float4 v[4];
  float ss = 0.f;
  #pragma unroll
  for (int j = 0; j < 4; ++j) {
    v[j] = xr[j*256 + threadIdx.x];
    ss += v[j].x*v[j].x + v[j].y*v[j].y + v[j].z*v[j].z + v[j].w*v[j].w;
  }
  #pragma unroll
  for (int off = 1; off < 64; off <<= 1) ss += __shfl_xor(ss, off);
  __shared__ float red[4];
  if ((threadIdx.x & 63) == 0) red[threadIdx.x >> 6] = ss;
  __syncthreads();
  ss = red[0] + red[1] + red[2] + red[3];
  __syncthreads();
  float rn = rsqrtf(ss / (float)HID + 1e-6f);
  float4 y[4];
  float am = 0.f;
  #pragma unroll
  for (int j = 0; j < 4; ++j) {
    float4 wv = wr[j*256 + threadIdx.x];
    y[j].x = v[j].x * rn * wv.x; y[j].y = v[j].y * rn * wv.y;
    y[j].z = v[j].z * rn * wv.z; y[j].w = v[j].w * rn * wv.w;
    am = fmaxf(am, fmaxf(fmaxf(fabsf(y[j].x), fabsf(y[j].y)), fmaxf(fabsf(y[j].z), fabsf(y[j].w))));
  }
  #pragma unroll
  for (int off = 1; off < 64; off <<= 1) am = fmaxf(am, __shfl_xor(am, off));
  if ((threadIdx.x & 63) == 0) red[threadIdx.x >> 6] = am;
  __syncthreads();
  am = fmaxf(fmaxf(red[0], red[1]), fmaxf(red[2], red[3]));
  float amc = fmaxf(am, 1e-5f);
  float s = 127.0f / amc;
  int* oq = (int*)(yq + row*HID);
  #pragma unroll
  for (int j = 0; j < 4; ++j)
    oq[j*256 + threadIdx.x] = pack4i8(y[j].x, y[j].y, y[j].z, y[j].w, s, -128.f, 127.f);
  if (threadIdx.x == 0) ys[row] = amc / 127.0f;
}

extern "C" void kernel_launch(void* const* d_in, const int* in_sizes, int n_in,
                              void* d_out, int out_size, void* d_ws, size_t ws_size,
                              hipStream_t stream) {
  const float* hs    = (const float*)d_in[0];
  const float* w_q   = (const float*)d_in[2];
  const float* w_k   = (const float*)d_in[3];
  const float* w_v   = (const float*)d_in[4];
  const float* w_o   = (const float*)d_in[5];
  const float* subln = (const float*)d_in[6];

  char* ws = (char*)d_ws;
  char*  wqq = (char*)(ws + 0L);                  // 16777216 (i8)
  char*  wqk = (char*)(ws + 16777216L);           // 4194304
  char*  wqv = (char*)(ws + 20971520L);           // 4194304
  char*  wqo = (char*)(ws + 25165824L);           // 16777216
  char*  xq  = (char*)(ws + 41943040L);           // 8388608
  float* ao  = (float*)(ws + 50331648L);          // 33554432 (fp32 attention out)
  char*  yq  = (char*)(ws + 83886080L);           // 8388608  (i8 rmsnorm out)
  u16*   qb  = (u16*)(ws + 92274688L);            // 16777216 (bf16 rope'd Q)
  u16*   kb  = (u16*)(ws + 109051904L);           // 4194304  (bf16 rope'd K)
  u16*   vtb = (u16*)(ws + 113246208L);           // 4194304  (bf16 V^T)
  float* cosb= (float*)(ws + 117440512L);         // 262144
  float* sinb= (float*)(ws + 117702656L);         // 262144
  float* xs  = (float*)(ws + 117964800L);         // 8192
  float* ys  = (float*)(ws + 117972992L);         // 8192
  float* wsc = (float*)(ws + 117981184L);         // 64
  float* par = (float*)(ws + 117981248L);         // 16384
  float* out = (float*)d_out;

  // 1. weight scales (merged)
  k_abssum4<<<2560, 256, 0, stream>>>(w_q, w_k, w_v, w_o, par);
  k_wscale<<<1, 256, 0, stream>>>(par, wsc);

  // 2. quantize weights (merged, ternary i8) + rope tables + act quant
  k_quantw8_all<<<40960, 256, 0, stream>>>(w_q, w_k, w_v, w_o, wqq, wqk, wqv, wqo, wsc);
  k_ropetab<<<256, 256, 0, stream>>>(cosb, sinb);
  k_actq8<<<NROWS, 256, 0, stream>>>(hs, xq, xs);

  // 3. merged Q/K/V i8 GEMM with fused RoPE (Q,K) and transposed-bf16 (V) epilogues
  k_gemm8_qkv<<<768, 256, 0, stream>>>(xq, wqq, wqk, wqv, qb, kb, vtb, xs, wsc, cosb, sinb);

  // 4. attention
  k_attn<<<dim3(8, 32, 2), 256, 0, stream>>>(qb, kb, vtb, ao);

  // 5. rmsnorm + act quant
  k_rmsq8<<<NROWS, 256, 0, stream>>>(ao, subln, yq, ys);

  // 6. output i8 GEMM
  k_gemm8<<<dim3(32, 16), 256, 0, stream>>>(yq, wqo, out, ys, wsc, 3, NROWS, 4096, 4096);
}

// Round 5
// 297.191 us; speedup vs baseline: 2.6978x; 1.0181x over previous
//
#include <hip/hip_runtime.h>
#include <hip/hip_bf16.h>
#include <cstdint>

typedef unsigned short u16;
typedef __bf16 bf16x8 __attribute__((ext_vector_type(8)));
typedef float f32x4 __attribute__((ext_vector_type(4)));
typedef int i32x4 __attribute__((ext_vector_type(4)));

#define SEQ 1024
#define HID 4096
#define NHQ 32
#define NKVH 8
#define HDIM 128
#define NB 2
#define NROWS (NB*SEQ)

static __device__ __forceinline__ u16 f2bf(float x) {
  __hip_bfloat16 h = __float2bfloat16(x);
  return *reinterpret_cast<u16*>(&h);
}

static __device__ __forceinline__ void gload16(const void* g, void* l) {
  __builtin_amdgcn_global_load_lds((__attribute__((address_space(1))) void*)(void*)g,
                                   (__attribute__((address_space(3))) void*)l, 16, 0, 0);
}

static __device__ __forceinline__ int pack4i8(float a, float b, float c, float d,
                                              float s, float lo, float hi) {
  int x0 = (int)fminf(fmaxf(rintf(a*s), lo), hi);
  int x1 = (int)fminf(fmaxf(rintf(b*s), lo), hi);
  int x2 = (int)fminf(fmaxf(rintf(c*s), lo), hi);
  int x3 = (int)fminf(fmaxf(rintf(d*s), lo), hi);
  return (x0 & 255) | ((x1 & 255) << 8) | ((x2 & 255) << 16) | ((x3 & 255) << 24);
}

// ---------------- merged weight abs-sum (pass 1): 2560 blocks ----------------
__global__ __launch_bounds__(256) void k_abssum4(const float* __restrict__ wq_, const float* __restrict__ wk_,
                                                 const float* __restrict__ wv_, const float* __restrict__ wo_,
                                                 float* __restrict__ partial) {
  int bx = blockIdx.x;
  const float* w; long n4; int pbase, lb, nb;
  if (bx < 1024)      { w = wq_; n4 = 4194304; pbase = 0;    lb = bx;        nb = 1024; }
  else if (bx < 1280) { w = wk_; n4 = 1048576; pbase = 1024; lb = bx - 1024; nb = 256; }
  else if (bx < 1536) { w = wv_; n4 = 1048576; pbase = 1280; lb = bx - 1280; nb = 256; }
  else                { w = wo_; n4 = 4194304; pbase = 1536; lb = bx - 1536; nb = 1024; }
  float s = 0.f;
  long stride = (long)nb * 256;
  const float4* w4 = (const float4*)w;
  for (long j = (long)lb*256 + threadIdx.x; j < n4; j += stride) {
    float4 v = w4[j];
    s += fabsf(v.x) + fabsf(v.y) + fabsf(v.z) + fabsf(v.w);
  }
  #pragma unroll
  for (int off = 1; off < 64; off <<= 1) s += __shfl_xor(s, off);
  __shared__ float red[4];
  if ((threadIdx.x & 63) == 0) red[threadIdx.x >> 6] = s;
  __syncthreads();
  if (threadIdx.x == 0) partial[pbase + lb] = red[0] + red[1] + red[2] + red[3];
}

// ---------------- weight scales (pass 2) ----------------
__global__ __launch_bounds__(256) void k_wscale(const float* __restrict__ partial,
                                                float* __restrict__ wsc) {
  __shared__ float red[4];
  const float nelem[4] = {16777216.f, 4194304.f, 4194304.f, 16777216.f};
  const int pbase[4] = {0, 1024, 1280, 1536};
  const int pcnt[4]  = {1024, 256, 256, 1024};
  for (int wi = 0; wi < 4; ++wi) {
    float s = 0.f;
    for (int j = threadIdx.x; j < pcnt[wi]; j += 256) s += partial[pbase[wi] + j];
    #pragma unroll
    for (int off = 1; off < 64; off <<= 1) s += __shfl_xor(s, off);
    if ((threadIdx.x & 63) == 0) red[threadIdx.x >> 6] = s;
    __syncthreads();
    if (threadIdx.x == 0) wsc[wi] = fmaxf((red[0]+red[1]+red[2]+red[3]) / nelem[wi], 1e-5f);
    __syncthreads();
  }
}

// ---------------- merged ternary weight quantize -> int8 (40960 blocks) ----------------
// For Wq/Wk (idx 0,1): rows permuted so RoPE pairs (2t,2t+1) -> (t, t+16) within each
// 32-row group. GEMM epilogue then finds both pair elements in one lane (acc ni, ni+1).
__global__ __launch_bounds__(256) void k_quantw8_all(const float* __restrict__ wq_, const float* __restrict__ wk_,
                                                     const float* __restrict__ wv_, const float* __restrict__ wo_,
                                                     char* __restrict__ oq_, char* __restrict__ ok_,
                                                     char* __restrict__ ov_, char* __restrict__ oo_,
                                                     const float* __restrict__ wsc) {
  int bx = blockIdx.x;
  const float* src; char* dst; int idx; long base;
  if (bx < 16384)      { src = wq_; dst = oq_; idx = 0; base = bx; }
  else if (bx < 20480) { src = wk_; dst = ok_; idx = 1; base = bx - 16384; }
  else if (bx < 24576) { src = wv_; dst = ov_; idx = 2; base = bx - 20480; }
  else                 { src = wo_; dst = oo_; idx = 3; base = bx - 24576; }
  long j = base*256 + threadIdx.x;        // float4 index; 1024 per weight row
  long oj = j;
  if (idx <= 1) {
    long row = j >> 10;
    int u = (int)(row & 31);
    long prow = (row & ~31L) | (long)((u >> 1) | ((u & 1) << 4));
    oj = (prow << 10) | (j & 1023);
  }
  float inv = 1.0f / wsc[idx];
  float4 v = ((const float4*)src)[j];
  ((int*)dst)[oj] = pack4i8(v.x, v.y, v.z, v.w, inv, -1.f, 1.f);
}

// ---------------- per-row activation quantize (hidden) -> int8 ----------------
__global__ __launch_bounds__(256) void k_actq8(const float* __restrict__ x, char* __restrict__ xq,
                                               float* __restrict__ xs) {
  long row = blockIdx.x;
  const float4* xr = (const float4*)(x + row*HID);
  float4 v[4];
  float am = 0.f;
  #pragma unroll
  for (int j = 0; j < 4; ++j) {
    v[j] = xr[j*256 + threadIdx.x];
    am = fmaxf(am, fmaxf(fmaxf(fabsf(v[j].x), fabsf(v[j].y)), fmaxf(fabsf(v[j].z), fabsf(v[j].w))));
  }
  #pragma unroll
  for (int off = 1; off < 64; off <<= 1) am = fmaxf(am, __shfl_xor(am, off));
  __shared__ float red[4];
  if ((threadIdx.x & 63) == 0) red[threadIdx.x >> 6] = am;
  __syncthreads();
  am = fmaxf(fmaxf(red[0], red[1]), fmaxf(red[2], red[3]));
  float amc = fmaxf(am, 1e-5f);
  float s = 127.0f / amc;
  int* oq = (int*)(xq + row*HID);
  #pragma unroll
  for (int j = 0; j < 4; ++j)
    oq[j*256 + threadIdx.x] = pack4i8(v[j].x, v[j].y, v[j].z, v[j].w, s, -128.f, 127.f);
  if (threadIdx.x == 0) xs[row] = amc / 127.0f;
}

// ---------------- i8 O-GEMM: 64x128 tile, dbuf prefetch, 4 blocks/CU ----------------
__global__ __launch_bounds__(256, 4) void k_gemm8(const char* __restrict__ A, const char* __restrict__ W,
                                                  float* __restrict__ C, const float* __restrict__ arow,
                                                  const float* __restrict__ wsc, int widx,
                                                  int M, int N, int K) {
  __shared__ char As[2][64*64] __attribute__((aligned(16)));
  __shared__ char Ws_[2][128*64] __attribute__((aligned(16)));
  int t = threadIdx.x;
  int l = (blockIdx.x & 7) * 128 + (blockIdx.x >> 3);   // XCD-bijective swizzle (1024%8==0)
  int bn = l >> 5, bm = l & 31;
  const char* Ab = A + (long)bm*64*K;
  const char* Wb = W + (long)bn*128*K;
  int lane = t & 63, wid = t >> 6;
  int wr = wid >> 1, wc = wid & 1;
  int lrow = lane & 15, l8 = lane >> 4;
  int xsw = (lrow >> 1) & 3;
  int ch0 = (l8 ^ xsw) * 16;
  i32x4 zero = {0, 0, 0, 0};
  i32x4 acc[2][4];
  #pragma unroll
  for (int mi = 0; mi < 2; ++mi)
    #pragma unroll
    for (int ni = 0; ni < 4; ++ni) acc[mi][ni] = zero;

  int r0 = t >> 2;
  int c0 = ((t & 3) ^ ((t >> 3) & 3)) * 16;   // pre-swizzled global chunk (rule #21)
  auto stage = [&](int buf, int kt) {
    gload16(Ab + (long)r0*K + kt*64 + c0, &As[buf][t*16]);
    gload16(Wb + (long)r0*K + kt*64 + c0, &Ws_[buf][t*16]);
    gload16(Wb + (long)(r0+64)*K + kt*64 + c0, &Ws_[buf][(t+256)*16]);
  };

  int nk = K >> 6;
  stage(0, 0);
  __syncthreads();
  int cur = 0;
  for (int kt = 0; kt < nk; ++kt) {
    if (kt + 1 < nk) stage(cur ^ 1, kt + 1);
    i32x4 af[2], bfr[4];
    #pragma unroll
    for (int mi = 0; mi < 2; ++mi) af[mi] = *(const i32x4*)&As[cur][(wr*32 + mi*16 + lrow)*64 + ch0];
    #pragma unroll
    for (int ni = 0; ni < 4; ++ni) bfr[ni] = *(const i32x4*)&Ws_[cur][(wc*64 + ni*16 + lrow)*64 + ch0];
    __builtin_amdgcn_s_setprio(1);
    #pragma unroll
    for (int mi = 0; mi < 2; ++mi)
      #pragma unroll
      for (int ni = 0; ni < 4; ++ni)
        acc[mi][ni] = __builtin_amdgcn_mfma_i32_16x16x64_i8(af[mi], bfr[ni], acc[mi][ni], 0, 0, 0);
    __builtin_amdgcn_s_setprio(0);
    __syncthreads();
    cur ^= 1;
  }
  float ws = wsc[widx];
  #pragma unroll
  for (int mi = 0; mi < 2; ++mi)
    #pragma unroll
    for (int r = 0; r < 4; ++r) {
      int row = bm*64 + wr*32 + mi*16 + l8*4 + r;
      float sc = arow[row] * ws;
      #pragma unroll
      for (int ni = 0; ni < 4; ++ni) {
        int col = bn*128 + wc*64 + ni*16 + lrow;
        C[(long)row*N + col] = (float)acc[mi][ni][r] * sc;
      }
    }
}

// ---------------- merged i8 QKV GEMM, dbuf prefetch, fused RoPE (no shfl) ----------------
// logical bx<512: Q -> Qb bf16 [b][32][s][d]; <640: K -> Kb bf16 [b][8][s][d]; else V -> Vt [b][8][d][s]
__global__ __launch_bounds__(256) void k_gemm8_qkv(const char* __restrict__ A,
    const char* __restrict__ Wq, const char* __restrict__ Wk, const char* __restrict__ Wv,
    u16* __restrict__ Qb, u16* __restrict__ Kb, u16* __restrict__ Vt,
    const float* __restrict__ arow, const float* __restrict__ wsc,
    const float* __restrict__ cosb, const float* __restrict__ sinb) {
  const int K = 4096;
  int bx = (blockIdx.x & 7) * 96 + (blockIdx.x >> 3);   // XCD-bijective swizzle (768%8==0)
  int kind, bm, bn;
  const char* W;
  if (bx < 512)      { kind = 0; bm = bx >> 5;          bn = bx & 31; W = Wq; }
  else if (bx < 640) { kind = 1; bm = (bx - 512) >> 3;  bn = bx & 7;  W = Wk; }
  else               { kind = 2; bm = (bx - 640) >> 3;  bn = bx & 7;  W = Wv; }

  __shared__ char As[2][128*64] __attribute__((aligned(16)));
  __shared__ char Ws_[2][128*64] __attribute__((aligned(16)));
  int t = threadIdx.x;
  const char* Ab = A + (long)bm*128*K;
  const char* Wb = W + (long)bn*128*K;
  int lane = t & 63, wid = t >> 6;
  int wr = wid >> 1, wc = wid & 1;
  int lrow = lane & 15, l8 = lane >> 4;
  int xsw = (lrow >> 1) & 3;
  int ch0 = (l8 ^ xsw) * 16;
  i32x4 zero = {0, 0, 0, 0};
  i32x4 acc[4][4];
  #pragma unroll
  for (int mi = 0; mi < 4; ++mi)
    #pragma unroll
    for (int ni = 0; ni < 4; ++ni) acc[mi][ni] = zero;

  int f0 = t, f1 = t + 256;
  int r0 = f0 >> 2, c0 = ((f0 & 3) ^ ((f0 >> 3) & 3)) * 16;
  int r1 = f1 >> 2;
  auto stage = [&](int buf, int kt) {
    gload16(Ab + (long)r0*K + kt*64 + c0, &As[buf][f0*16]);
    gload16(Ab + (long)r1*K + kt*64 + c0, &As[buf][f1*16]);
    gload16(Wb + (long)r0*K + kt*64 + c0, &Ws_[buf][f0*16]);
    gload16(Wb + (long)r1*K + kt*64 + c0, &Ws_[buf][f1*16]);
  };

  stage(0, 0);
  __syncthreads();
  int cur = 0;
  for (int kt = 0; kt < (K >> 6); ++kt) {
    if (kt + 1 < (K >> 6)) stage(cur ^ 1, kt + 1);
    i32x4 af[4], bfr[4];
    #pragma unroll
    for (int mi = 0; mi < 4; ++mi) af[mi] = *(const i32x4*)&As[cur][(wr*64 + mi*16 + lrow)*64 + ch0];
    #pragma unroll
    for (int ni = 0; ni < 4; ++ni) bfr[ni] = *(const i32x4*)&Ws_[cur][(wc*64 + ni*16 + lrow)*64 + ch0];
    __builtin_amdgcn_s_setprio(1);
    #pragma unroll
    for (int mi = 0; mi < 4; ++mi)
      #pragma unroll
      for (int ni = 0; ni < 4; ++ni)
        acc[mi][ni] = __builtin_amdgcn_mfma_i32_16x16x64_i8(af[mi], bfr[ni], acc[mi][ni], 0, 0, 0);
    __builtin_amdgcn_s_setprio(0);
    __syncthreads();
    cur ^= 1;
  }

  if (kind == 2) {
    float ws = wsc[2];
    #pragma unroll
    for (int mi = 0; mi < 4; ++mi) {
      int row0 = bm*128 + wr*64 + mi*16 + l8*4;
      int bidx = row0 >> 10, s0 = row0 & 1023;
      #pragma unroll
      for (int ni = 0; ni < 4; ++ni) {
        int col = bn*128 + wc*64 + ni*16 + lrow;
        int hkv = col >> 7, d = col & 127;
        ushort4 o4;
        o4.x = f2bf((float)acc[mi][ni][0] * arow[row0+0] * ws);
        o4.y = f2bf((float)acc[mi][ni][1] * arow[row0+1] * ws);
        o4.z = f2bf((float)acc[mi][ni][2] * arow[row0+2] * ws);
        o4.w = f2bf((float)acc[mi][ni][3] * arow[row0+3] * ws);
        *(ushort4*)&Vt[(((long)bidx*NKVH + hkv)*HDIM + d)*SEQ + s0] = o4;
      }
    }
  } else {
    // Weight rows were permuted: physical col c (w=c&31) holds feature
    // f = (c&~31) + (w<16 ? 2w : 2(w-16)+1). So (acc[mi][2j], acc[mi][2j+1]) are the
    // RoPE pair (B+2*lrow, B+2*lrow+1), B = bn*128 + wc*64 + j*32 — lane-local.
    float ws = wsc[kind];
    u16* dst = kind ? Kb : Qb;
    int nh = kind ? NKVH : NHQ;
    #pragma unroll
    for (int mi = 0; mi < 4; ++mi) {
      #pragma unroll
      for (int r = 0; r < 4; ++r) {
        int row = bm*128 + wr*64 + mi*16 + l8*4 + r;
        int bidx = row >> 10, s = row & 1023;
        float sc = arow[row] * ws;
        #pragma unroll
        for (int j = 0; j < 2; ++j) {
          float a  = (float)acc[mi][2*j][r] * sc;
          float b2 = (float)acc[mi][2*j+1][r] * sc;
          int B = bn*128 + wc*64 + j*32;
          int h = B >> 7;
          int d = (B & 127) + 2*lrow;
          int i = d >> 1;
          float cc = cosb[(s << 6) + i], sn = sinb[(s << 6) + i];
          ushort2 o2;
          o2.x = f2bf(a*cc - b2*sn);
          o2.y = f2bf(a*sn + b2*cc);
          *(ushort2*)&dst[(((long)bidx*nh + h)*SEQ + s)*HDIM + d] = o2;
        }
      }
    }
  }
}

// ---------------- rope tables ----------------
__global__ __launch_bounds__(256) void k_ropetab(float* __restrict__ cosb, float* __restrict__ sinb) {
  int idx = blockIdx.x*256 + threadIdx.x;
  int s = idx >> 6, i = idx & 63;
  float e = (2.0f * (float)i) / 128.0f;
  float inv = 1.0f / powf(500000.0f, e);
  float f = (float)s * inv;
  cosb[idx] = cosf(f);
  sinb[idx] = sinf(f);
}

// ---------------- causal GQA flash attention, LDS-staged, causal-paired ----------------
__global__ __launch_bounds__(256) void k_attn(const u16* __restrict__ qb, const u16* __restrict__ kb,
                                              const u16* __restrict__ vt, float* __restrict__ ao) {
  int p = blockIdx.x, h = blockIdx.y, b = blockIdx.z;
  int t = threadIdx.x, lane = t & 63, wid = t >> 6;
  int lrow = lane & 15, l8 = lane >> 4;
  int x7 = lrow & 7;

  __shared__ u16 Ks[2][64*128] __attribute__((aligned(16)));
  __shared__ u16 Vs[2][128*64] __attribute__((aligned(16)));
  __shared__ u16 Ps[4][16][72] __attribute__((aligned(16)));

  const u16* kp = kb + ((long)(b*NKVH + (h >> 2)))*SEQ*HDIM;
  const u16* vp = vt + ((long)(b*NKVH + (h >> 2)))*HDIM*SEQ;

  auto stageK = [&](int buf, int j) {
    const u16* src = kp + (long)j*64*HDIM;
    #pragma unroll
    for (int i = 0; i < 4; ++i) {
      int r0 = wid*16 + i*4;
      int row = r0 + (lane >> 4);
      int cg = (lane & 15) ^ (row & 7);
      gload16(src + (long)row*HDIM + cg*8, &Ks[buf][r0*HDIM]);
    }
  };
  auto stageV = [&](int buf, int j) {
    #pragma unroll
    for (int i = 0; i < 4; ++i) {
      int r0 = wid*32 + i*8;
      int row = r0 + (lane >> 3);
      int cg = (lane & 7) ^ (row & 7);
      gload16(vp + (long)row*SEQ + j*64 + cg*8, &Vs[buf][r0*64]);
    }
  };

  for (int phase = 0; phase < 2; ++phase) {
    int qt = phase ? (15 - p) : p;
    int q0 = qt*64 + wid*16;
    const u16* qp = qb + (((long)(b*NHQ + h))*SEQ + q0)*HDIM;
    bf16x8 qf[4];
    #pragma unroll
    for (int ks = 0; ks < 4; ++ks) qf[ks] = *(const bf16x8*)&qp[lrow*HDIM + ks*32 + l8*8];
    f32x4 zero = {0.f, 0.f, 0.f, 0.f};
    f32x4 o[8];
    #pragma unroll
    for (int f = 0; f < 8; ++f) o[f] = zero;
    float m[4], ll[4];
    #pragma unroll
    for (int r = 0; r < 4; ++r) { m[r] = -1e30f; ll[r] = 0.f; }

    int nj = qt + 1;
    stageK(0, 0); stageV(0, 0);
    __syncthreads();
    int cur = 0;
    for (int j = 0; j < nj; ++j) {
      if (j + 1 < nj) { stageK(cur ^ 1, j + 1); stageV(cur ^ 1, j + 1); }
      const u16* Kc = Ks[cur];
      const u16* Vc = Vs[cur];
      f32x4 sc4[4];
      #pragma unroll
      for (int ni = 0; ni < 4; ++ni) sc4[ni] = zero;
      __builtin_amdgcn_s_setprio(1);
      #pragma unroll
      for (int ni = 0; ni < 4; ++ni) {
        int row = ni*16 + lrow;
        #pragma unroll
        for (int ks = 0; ks < 4; ++ks) {
          int cl = (ks*4 + l8) ^ x7;
          bf16x8 kfr = *(const bf16x8*)&Kc[row*HDIM + cl*8];
          sc4[ni] = __builtin_amdgcn_mfma_f32_16x16x32_bf16(qf[ks], kfr, sc4[ni], 0, 0, 0);
        }
      }
      __builtin_amdgcn_s_setprio(0);
      const float scale = 0.08838834764831845f;
      float pm[4] = {-1e30f, -1e30f, -1e30f, -1e30f};
      float pv[4][4];
      bool diag = (j == qt);
      #pragma unroll
      for (int ni = 0; ni < 4; ++ni) {
        int kv = j*64 + ni*16 + lrow;
        #pragma unroll
        for (int r = 0; r < 4; ++r) {
          int qr = q0 + l8*4 + r;
          float val = sc4[ni][r] * scale;
          if (diag && kv > qr) val = -1e30f;
          pv[ni][r] = val;
          pm[r] = fmaxf(pm[r], val);
        }
      }
      #pragma unroll
      for (int r = 0; r < 4; ++r) {
        #pragma unroll
        for (int off = 1; off < 16; off <<= 1) pm[r] = fmaxf(pm[r], __shfl_xor(pm[r], off));
      }
      float fr[4], rs[4];
      #pragma unroll
      for (int r = 0; r < 4; ++r) {
        float nm = fmaxf(m[r], pm[r]);
        fr[r] = __expf(m[r] - nm);
        m[r] = nm; rs[r] = 0.f;
      }
      #pragma unroll
      for (int ni = 0; ni < 4; ++ni)
        #pragma unroll
        for (int r = 0; r < 4; ++r) {
          float pe = __expf(pv[ni][r] - m[r]);
          pv[ni][r] = pe; rs[r] += pe;
        }
      #pragma unroll
      for (int r = 0; r < 4; ++r) {
        #pragma unroll
        for (int off = 1; off < 16; off <<= 1) rs[r] += __shfl_xor(rs[r], off);
        ll[r] = ll[r]*fr[r] + rs[r];
      }
      #pragma unroll
      for (int f = 0; f < 8; ++f) {
        o[f][0] *= fr[0]; o[f][1] *= fr[1]; o[f][2] *= fr[2]; o[f][3] *= fr[3];
      }
      #pragma unroll
      for (int ni = 0; ni < 4; ++ni)
        #pragma unroll
        for (int r = 0; r < 4; ++r)
          Ps[wid][l8*4 + r][ni*16 + lrow] = f2bf(pv[ni][r]);
      bf16x8 pf0 = *(const bf16x8*)&Ps[wid][lrow][l8*8];
      bf16x8 pf1 = *(const bf16x8*)&Ps[wid][lrow][32 + l8*8];
      __builtin_amdgcn_s_setprio(1);
      #pragma unroll
      for (int f = 0; f < 8; ++f) {
        int d = f*16 + lrow;
        bf16x8 v0 = *(const bf16x8*)&Vc[d*64 + ((l8) ^ x7)*8];
        bf16x8 v1 = *(const bf16x8*)&Vc[d*64 + ((4 + l8) ^ x7)*8];
        o[f] = __builtin_amdgcn_mfma_f32_16x16x32_bf16(pf0, v0, o[f], 0, 0, 0);
        o[f] = __builtin_amdgcn_mfma_f32_16x16x32_bf16(pf1, v1, o[f], 0, 0, 0);
      }
      __builtin_amdgcn_s_setprio(0);
      __syncthreads();
      cur ^= 1;
    }
    float invl[4];
    #pragma unroll
    for (int r = 0; r < 4; ++r) invl[r] = 1.0f / ll[r];
    #pragma unroll
    for (int f = 0; f < 8; ++f)
      #pragma unroll
      for (int r = 0; r < 4; ++r) {
        long row = (long)b*SEQ + q0 + l8*4 + r;
        ao[row*HID + h*HDIM + f*16 + lrow] = o[f][r] * invl[r];
      }
    __syncthreads();
  }
}

// ---------------- fused rmsnorm + act quant -> int8 ----------------
__global__ __launch_bounds__(256) void k_rmsq8(const float* __restrict__ x, const float* __restrict__ w,
                                               char* __restrict__ yq, float* __restrict__ ys) {
  long row = blockIdx.x;
  const float4* xr = (const float4*)(x + row*HID);
  const float4* wr = (const float4*)w;
  float4 v[4];
  float ss = 0.f;
  #pragma unroll
  for (int j = 0; j < 4; ++j) {
    v[j] = xr[j*256 + threadIdx.x];
    ss += v[j].x*v[j].x + v[j].y*v[j].y + v[j].z*v[j].z + v[j].w*v[j].w;
  }
  #pragma unroll
  for (int off = 1; off < 64; off <<= 1) ss += __shfl_xor(ss, off);
  __shared__ float red[4];
  if ((threadIdx.x & 63) == 0) red[threadIdx.x >> 6] = ss;
  __syncthreads();
  ss = red[0] + red[1] + red[2] + red[3];
  __syncthreads();
  float rn = rsqrtf(ss / (float)HID + 1e-6f);
  float4 y[4];
  float am = 0.f;
  #pragma unroll
  for (int j = 0; j < 4; ++j) {
    float4 wv = wr[j*256 + threadIdx.x];
    y[j].x = v[j].x * rn * wv.x; y[j].y = v[j].y * rn * wv.y;
    y[j].z = v[j].z * rn * wv.z; y[j].w = v[j].w * rn * wv.w;
    am = fmaxf(am, fmaxf(fmaxf(fabsf(y[j].x), fabsf(y[j].y)), fmaxf(fabsf(y[j].z), fabsf(y[j].w))));
  }
  #pragma unroll
  for (int off = 1; off < 64; off <<= 1) am = fmaxf(am, __shfl_xor(am, off));
  if ((threadIdx.x & 63) == 0) red[threadIdx.x >> 6] = am;
  __syncthreads();
  am = fmaxf(fmaxf(red[0], red[1]), fmaxf(red[2], red[3]));
  float amc = fmaxf(am, 1e-5f);
  float s = 127.0f / amc;
  int* oq = (int*)(yq + row*HID);
  #pragma unroll
  for (int j = 0; j < 4; ++j)
    oq[j*256 + threadIdx.x] = pack4i8(y[j].x, y[j].y, y[j].z, y[j].w, s, -128.f, 127.f);
  if (threadIdx.x == 0) ys[row] = amc / 127.0f;
}

extern "C" void kernel_launch(void* const* d_in, const int* in_sizes, int n_in,
                              void* d_out, int out_size, void* d_ws, size_t ws_size,
                              hipStream_t stream) {
  const float* hs    = (const float*)d_in[0];
  const float* w_q   = (const float*)d_in[2];
  const float* w_k   = (const float*)d_in[3];
  const float* w_v   = (const float*)d_in[4];
  const float* w_o   = (const float*)d_in[5];
  const float* subln = (const float*)d_in[6];

  char* ws = (char*)d_ws;
  char*  wqq = (char*)(ws + 0L);                  // 16777216 (i8, rows perm'd)
  char*  wqk = (char*)(ws + 16777216L);           // 4194304  (i8, rows perm'd)
  char*  wqv = (char*)(ws + 20971520L);           // 4194304
  char*  wqo = (char*)(ws + 25165824L);           // 16777216
  char*  xq  = (char*)(ws + 41943040L);           // 8388608
  float* ao  = (float*)(ws + 50331648L);          // 33554432 (fp32 attention out)
  char*  yq  = (char*)(ws + 83886080L);           // 8388608  (i8 rmsnorm out)
  u16*   qb  = (u16*)(ws + 92274688L);            // 16777216 (bf16 rope'd Q)
  u16*   kb  = (u16*)(ws + 109051904L);           // 4194304  (bf16 rope'd K)
  u16*   vtb = (u16*)(ws + 113246208L);           // 4194304  (bf16 V^T)
  float* cosb= (float*)(ws + 117440512L);         // 262144
  float* sinb= (float*)(ws + 117702656L);         // 262144
  float* xs  = (float*)(ws + 117964800L);         // 8192
  float* ys  = (float*)(ws + 117972992L);         // 8192
  float* wsc = (float*)(ws + 117981184L);         // 64
  float* par = (float*)(ws + 117981248L);         // 16384
  float* out = (float*)d_out;

  // 1. weight scales (merged)
  k_abssum4<<<2560, 256, 0, stream>>>(w_q, w_k, w_v, w_o, par);
  k_wscale<<<1, 256, 0, stream>>>(par, wsc);

  // 2. quantize weights (merged, ternary i8; Q/K rows perm'd for lane-local RoPE pairs)
  k_quantw8_all<<<40960, 256, 0, stream>>>(w_q, w_k, w_v, w_o, wqq, wqk, wqv, wqo, wsc);
  k_ropetab<<<256, 256, 0, stream>>>(cosb, sinb);
  k_actq8<<<NROWS, 256, 0, stream>>>(hs, xq, xs);

  // 3. merged Q/K/V i8 GEMM, dbuf prefetch, fused shfl-free RoPE + V-transpose epilogues
  k_gemm8_qkv<<<768, 256, 0, stream>>>(xq, wqq, wqk, wqv, qb, kb, vtb, xs, wsc, cosb, sinb);

  // 4. attention
  k_attn<<<dim3(8, 32, 2), 256, 0, stream>>>(qb, kb, vtb, ao);

  // 5. rmsnorm + act quant
  k_rmsq8<<<NROWS, 256, 0, stream>>>(ao, subln, yq, ys);

  // 6. output i8 GEMM (64x128 tile, 4 blocks/CU)
  k_gemm8<<<1024, 256, 0, stream>>>(yq, wqo, out, ys, wsc, 3, NROWS, 4096, 4096);
}

// Round 6
// 277.017 us; speedup vs baseline: 2.8943x; 1.0728x over previous
//
#include <hip/hip_runtime.h>
#include <hip/hip_bf16.h>
#include <cstdint>

typedef unsigned short u16;
typedef __bf16 bf16x8 __attribute__((ext_vector_type(8)));
typedef float f32x4 __attribute__((ext_vector_type(4)));
typedef int i32x4 __attribute__((ext_vector_type(4)));

#define SEQ 1024
#define HID 4096
#define NHQ 32
#define NKVH 8
#define HDIM 128
#define NB 2
#define NROWS (NB*SEQ)

static __device__ __forceinline__ u16 f2bf(float x) {
  __hip_bfloat16 h = __float2bfloat16(x);
  return *reinterpret_cast<u16*>(&h);
}

static __device__ __forceinline__ void gload16(const void* g, void* l) {
  __builtin_amdgcn_global_load_lds((__attribute__((address_space(1))) void*)(void*)g,
                                   (__attribute__((address_space(3))) void*)l, 16, 0, 0);
}

static __device__ __forceinline__ int pack4i8(float a, float b, float c, float d,
                                              float s, float lo, float hi) {
  int x0 = (int)fminf(fmaxf(rintf(a*s), lo), hi);
  int x1 = (int)fminf(fmaxf(rintf(b*s), lo), hi);
  int x2 = (int)fminf(fmaxf(rintf(c*s), lo), hi);
  int x3 = (int)fminf(fmaxf(rintf(d*s), lo), hi);
  return (x0 & 255) | ((x1 & 255) << 8) | ((x2 & 255) << 16) | ((x3 & 255) << 24);
}

// ---------------- merged weight abs-sum (pass 1): 2560 blocks ----------------
__global__ __launch_bounds__(256) void k_abssum4(const float* __restrict__ wq_, const float* __restrict__ wk_,
                                                 const float* __restrict__ wv_, const float* __restrict__ wo_,
                                                 float* __restrict__ partial) {
  int bx = blockIdx.x;
  const float* w; long n4; int pbase, lb, nb;
  if (bx < 1024)      { w = wq_; n4 = 4194304; pbase = 0;    lb = bx;        nb = 1024; }
  else if (bx < 1280) { w = wk_; n4 = 1048576; pbase = 1024; lb = bx - 1024; nb = 256; }
  else if (bx < 1536) { w = wv_; n4 = 1048576; pbase = 1280; lb = bx - 1280; nb = 256; }
  else                { w = wo_; n4 = 4194304; pbase = 1536; lb = bx - 1536; nb = 1024; }
  float s = 0.f;
  long stride = (long)nb * 256;
  const float4* w4 = (const float4*)w;
  for (long j = (long)lb*256 + threadIdx.x; j < n4; j += stride) {
    float4 v = w4[j];
    s += fabsf(v.x) + fabsf(v.y) + fabsf(v.z) + fabsf(v.w);
  }
  #pragma unroll
  for (int off = 1; off < 64; off <<= 1) s += __shfl_xor(s, off);
  __shared__ float red[4];
  if ((threadIdx.x & 63) == 0) red[threadIdx.x >> 6] = s;
  __syncthreads();
  if (threadIdx.x == 0) partial[pbase + lb] = red[0] + red[1] + red[2] + red[3];
}

// ---------------- weight scales (pass 2) ----------------
__global__ __launch_bounds__(256) void k_wscale(const float* __restrict__ partial,
                                                float* __restrict__ wsc) {
  __shared__ float red[4];
  const float nelem[4] = {16777216.f, 4194304.f, 4194304.f, 16777216.f};
  const int pbase[4] = {0, 1024, 1280, 1536};
  const int pcnt[4]  = {1024, 256, 256, 1024};
  for (int wi = 0; wi < 4; ++wi) {
    float s = 0.f;
    for (int j = threadIdx.x; j < pcnt[wi]; j += 256) s += partial[pbase[wi] + j];
    #pragma unroll
    for (int off = 1; off < 64; off <<= 1) s += __shfl_xor(s, off);
    if ((threadIdx.x & 63) == 0) red[threadIdx.x >> 6] = s;
    __syncthreads();
    if (threadIdx.x == 0) wsc[wi] = fmaxf((red[0]+red[1]+red[2]+red[3]) / nelem[wi], 1e-5f);
    __syncthreads();
  }
}

// ---------------- merged ternary weight quantize -> int8 (40960 blocks) ----------------
__global__ __launch_bounds__(256) void k_quantw8_all(const float* __restrict__ wq_, const float* __restrict__ wk_,
                                                     const float* __restrict__ wv_, const float* __restrict__ wo_,
                                                     char* __restrict__ oq_, char* __restrict__ ok_,
                                                     char* __restrict__ ov_, char* __restrict__ oo_,
                                                     const float* __restrict__ wsc) {
  int bx = blockIdx.x;
  const float* src; char* dst; int idx; long base;
  if (bx < 16384)      { src = wq_; dst = oq_; idx = 0; base = bx; }
  else if (bx < 20480) { src = wk_; dst = ok_; idx = 1; base = bx - 16384; }
  else if (bx < 24576) { src = wv_; dst = ov_; idx = 2; base = bx - 20480; }
  else                 { src = wo_; dst = oo_; idx = 3; base = bx - 24576; }
  long j = base*256 + threadIdx.x;        // float4 index; 1024 per weight row
  long oj = j;
  if (idx <= 1) {
    long row = j >> 10;
    int u = (int)(row & 31);
    long prow = (row & ~31L) | (long)((u >> 1) | ((u & 1) << 4));
    oj = (prow << 10) | (j & 1023);
  }
  float inv = 1.0f / wsc[idx];
  float4 v = ((const float4*)src)[j];
  ((int*)dst)[oj] = pack4i8(v.x, v.y, v.z, v.w, inv, -1.f, 1.f);
}

// ---------------- per-row activation quantize (hidden) -> int8 ----------------
__global__ __launch_bounds__(256) void k_actq8(const float* __restrict__ x, char* __restrict__ xq,
                                               float* __restrict__ xs) {
  long row = blockIdx.x;
  const float4* xr = (const float4*)(x + row*HID);
  float4 v[4];
  float am = 0.f;
  #pragma unroll
  for (int j = 0; j < 4; ++j) {
    v[j] = xr[j*256 + threadIdx.x];
    am = fmaxf(am, fmaxf(fmaxf(fabsf(v[j].x), fabsf(v[j].y)), fmaxf(fabsf(v[j].z), fabsf(v[j].w))));
  }
  #pragma unroll
  for (int off = 1; off < 64; off <<= 1) am = fmaxf(am, __shfl_xor(am, off));
  __shared__ float red[4];
  if ((threadIdx.x & 63) == 0) red[threadIdx.x >> 6] = am;
  __syncthreads();
  am = fmaxf(fmaxf(red[0], red[1]), fmaxf(red[2], red[3]));
  float amc = fmaxf(am, 1e-5f);
  float s = 127.0f / amc;
  int* oq = (int*)(xq + row*HID);
  #pragma unroll
  for (int j = 0; j < 4; ++j)
    oq[j*256 + threadIdx.x] = pack4i8(v[j].x, v[j].y, v[j].z, v[j].w, s, -128.f, 127.f);
  if (threadIdx.x == 0) xs[row] = amc / 127.0f;
}

// ---------------- i8 O-GEMM: 64x128 tile, counted-vmcnt 3-buf pipeline ----------------
__global__ __launch_bounds__(256) void k_gemm8(const char* __restrict__ A, const char* __restrict__ W,
                                               float* __restrict__ C, const float* __restrict__ arow,
                                               const float* __restrict__ wsc, int widx,
                                               int M, int N, int K) {
  __shared__ char As[3][64*64] __attribute__((aligned(16)));
  __shared__ char Ws_[3][128*64] __attribute__((aligned(16)));
  int t = threadIdx.x;
  // supertile XCD map: xcd owns 16bm x 8bn square; bn-fastest within
  int bid = blockIdx.x;
  int xcd = bid & 7, w = bid >> 3;                 // w in 0..127
  int bm = ((xcd & 1) << 4) + (w >> 3);            // 0..31
  int bn = ((xcd >> 1) << 3) + (w & 7);            // 0..31
  const char* Ab = A + (long)bm*64*K;
  const char* Wb = W + (long)bn*128*K;
  int lane = t & 63, wid = t >> 6;
  int wr = wid >> 1, wc = wid & 1;
  int lrow = lane & 15, l8 = lane >> 4;
  int xsw = (lrow >> 1) & 3;
  int ch0 = (l8 ^ xsw) * 16;
  i32x4 zero = {0, 0, 0, 0};
  i32x4 acc[2][4];
  #pragma unroll
  for (int mi = 0; mi < 2; ++mi)
    #pragma unroll
    for (int ni = 0; ni < 4; ++ni) acc[mi][ni] = zero;

  int r0 = t >> 2;
  int c0 = ((t & 3) ^ ((t >> 3) & 3)) * 16;   // pre-swizzled global chunk (rule #21)
  auto stage = [&](int buf, int kt) {         // 3 VMEM ops per thread
    gload16(Ab + (long)r0*K + kt*64 + c0, &As[buf][t*16]);
    gload16(Wb + (long)r0*K + kt*64 + c0, &Ws_[buf][t*16]);
    gload16(Wb + (long)(r0+64)*K + kt*64 + c0, &Ws_[buf][(t+256)*16]);
  };

  int nk = K >> 6;                            // 64
  stage(0, 0); stage(1, 1);
  for (int kt = 0; kt < nk; ++kt) {
    if (kt + 2 < nk) {
      stage((kt + 2) % 3, kt + 2);
      asm volatile("s_waitcnt vmcnt(6)" ::: "memory");
    } else if (kt + 1 < nk) {
      asm volatile("s_waitcnt vmcnt(3)" ::: "memory");
    } else {
      asm volatile("s_waitcnt vmcnt(0)" ::: "memory");
    }
    __builtin_amdgcn_sched_barrier(0);
    __builtin_amdgcn_s_barrier();
    int cur = kt % 3;
    const char* Ac = &As[cur][0];
    const char* Wc = &Ws_[cur][0];
    i32x4 af[2], bfr[4];
    #pragma unroll
    for (int mi = 0; mi < 2; ++mi) af[mi] = *(const i32x4*)&Ac[(wr*32 + mi*16 + lrow)*64 + ch0];
    #pragma unroll
    for (int ni = 0; ni < 4; ++ni) bfr[ni] = *(const i32x4*)&Wc[(wc*64 + ni*16 + lrow)*64 + ch0];
    __builtin_amdgcn_s_setprio(1);
    #pragma unroll
    for (int mi = 0; mi < 2; ++mi)
      #pragma unroll
      for (int ni = 0; ni < 4; ++ni)
        acc[mi][ni] = __builtin_amdgcn_mfma_i32_16x16x64_i8(af[mi], bfr[ni], acc[mi][ni], 0, 0, 0);
    __builtin_amdgcn_s_setprio(0);
    asm volatile("s_waitcnt lgkmcnt(0)" ::: "memory");
    __builtin_amdgcn_sched_barrier(0);
    __builtin_amdgcn_s_barrier();
  }
  float ws = wsc[widx];
  #pragma unroll
  for (int mi = 0; mi < 2; ++mi)
    #pragma unroll
    for (int r = 0; r < 4; ++r) {
      int row = bm*64 + wr*32 + mi*16 + l8*4 + r;
      float sc = arow[row] * ws;
      #pragma unroll
      for (int ni = 0; ni < 4; ++ni) {
        int col = bn*128 + wc*64 + ni*16 + lrow;
        C[(long)row*N + col] = (float)acc[mi][ni][r] * sc;
      }
    }
}

// ---------------- merged i8 QKV GEMM, counted-vmcnt 3-buf pipeline, fused RoPE ----------------
// supertile XCD map: Q -> xcd owns 8bm x 8bn square; K/V -> 2bm x 8bn strip
__global__ __launch_bounds__(256) void k_gemm8_qkv(const char* __restrict__ A,
    const char* __restrict__ Wq, const char* __restrict__ Wk, const char* __restrict__ Wv,
    u16* __restrict__ Qb, u16* __restrict__ Kb, u16* __restrict__ Vt,
    const float* __restrict__ arow, const float* __restrict__ wsc,
    const float* __restrict__ cosb, const float* __restrict__ sinb) {
  const int K = 4096;
  int bid = blockIdx.x;
  int xcd = bid & 7, w = bid >> 3;                 // w in 0..95
  int kind, bm, bn;
  const char* W;
  if (w < 64)      { kind = 0; bm = ((xcd & 1) << 3) + (w >> 3); bn = ((xcd >> 1) << 3) + (w & 7); W = Wq; }
  else if (w < 80) { int u = w - 64; kind = 1; bm = (xcd << 1) + (u >> 3); bn = u & 7; W = Wk; }
  else             { int u = w - 80; kind = 2; bm = (xcd << 1) + (u >> 3); bn = u & 7; W = Wv; }

  __shared__ char As[3][128*64] __attribute__((aligned(16)));
  __shared__ char Ws_[3][128*64] __attribute__((aligned(16)));
  int t = threadIdx.x;
  const char* Ab = A + (long)bm*128*K;
  const char* Wb = W + (long)bn*128*K;
  int lane = t & 63, wid = t >> 6;
  int wr = wid >> 1, wc = wid & 1;
  int lrow = lane & 15, l8 = lane >> 4;
  int xsw = (lrow >> 1) & 3;
  int ch0 = (l8 ^ xsw) * 16;
  i32x4 zero = {0, 0, 0, 0};
  i32x4 acc[4][4];
  #pragma unroll
  for (int mi = 0; mi < 4; ++mi)
    #pragma unroll
    for (int ni = 0; ni < 4; ++ni) acc[mi][ni] = zero;

  int f0 = t, f1 = t + 256;
  int r0 = f0 >> 2, c0 = ((f0 & 3) ^ ((f0 >> 3) & 3)) * 16;
  int r1 = f1 >> 2;
  auto stage = [&](int buf, int kt) {         // 4 VMEM ops per thread
    gload16(Ab + (long)r0*K + kt*64 + c0, &As[buf][f0*16]);
    gload16(Ab + (long)r1*K + kt*64 + c0, &As[buf][f1*16]);
    gload16(Wb + (long)r0*K + kt*64 + c0, &Ws_[buf][f0*16]);
    gload16(Wb + (long)r1*K + kt*64 + c0, &Ws_[buf][f1*16]);
  };

  int nk = K >> 6;                            // 64
  stage(0, 0); stage(1, 1);
  for (int kt = 0; kt < nk; ++kt) {
    if (kt + 2 < nk) {
      stage((kt + 2) % 3, kt + 2);
      asm volatile("s_waitcnt vmcnt(8)" ::: "memory");
    } else if (kt + 1 < nk) {
      asm volatile("s_waitcnt vmcnt(4)" ::: "memory");
    } else {
      asm volatile("s_waitcnt vmcnt(0)" ::: "memory");
    }
    __builtin_amdgcn_sched_barrier(0);
    __builtin_amdgcn_s_barrier();
    int cur = kt % 3;
    const char* Ac = &As[cur][0];
    const char* Wc = &Ws_[cur][0];
    i32x4 af[4], bfr[4];
    #pragma unroll
    for (int mi = 0; mi < 4; ++mi) af[mi] = *(const i32x4*)&Ac[(wr*64 + mi*16 + lrow)*64 + ch0];
    #pragma unroll
    for (int ni = 0; ni < 4; ++ni) bfr[ni] = *(const i32x4*)&Wc[(wc*64 + ni*16 + lrow)*64 + ch0];
    __builtin_amdgcn_s_setprio(1);
    #pragma unroll
    for (int mi = 0; mi < 4; ++mi)
      #pragma unroll
      for (int ni = 0; ni < 4; ++ni)
        acc[mi][ni] = __builtin_amdgcn_mfma_i32_16x16x64_i8(af[mi], bfr[ni], acc[mi][ni], 0, 0, 0);
    __builtin_amdgcn_s_setprio(0);
    asm volatile("s_waitcnt lgkmcnt(0)" ::: "memory");
    __builtin_amdgcn_sched_barrier(0);
    __builtin_amdgcn_s_barrier();
  }

  if (kind == 2) {
    float ws = wsc[2];
    #pragma unroll
    for (int mi = 0; mi < 4; ++mi) {
      int row0 = bm*128 + wr*64 + mi*16 + l8*4;
      int bidx = row0 >> 10, s0 = row0 & 1023;
      #pragma unroll
      for (int ni = 0; ni < 4; ++ni) {
        int col = bn*128 + wc*64 + ni*16 + lrow;
        int hkv = col >> 7, d = col & 127;
        ushort4 o4;
        o4.x = f2bf((float)acc[mi][ni][0] * arow[row0+0] * ws);
        o4.y = f2bf((float)acc[mi][ni][1] * arow[row0+1] * ws);
        o4.z = f2bf((float)acc[mi][ni][2] * arow[row0+2] * ws);
        o4.w = f2bf((float)acc[mi][ni][3] * arow[row0+3] * ws);
        *(ushort4*)&Vt[(((long)bidx*NKVH + hkv)*HDIM + d)*SEQ + s0] = o4;
      }
    }
  } else {
    // Weight rows permuted at quant: (acc[mi][2j], acc[mi][2j+1]) are the RoPE pair
    // (B+2*lrow, B+2*lrow+1), B = bn*128 + wc*64 + j*32 — lane-local, no shfl.
    float ws = wsc[kind];
    u16* dst = kind ? Kb : Qb;
    int nh = kind ? NKVH : NHQ;
    #pragma unroll
    for (int mi = 0; mi < 4; ++mi) {
      #pragma unroll
      for (int r = 0; r < 4; ++r) {
        int row = bm*128 + wr*64 + mi*16 + l8*4 + r;
        int bidx = row >> 10, s = row & 1023;
        float sc = arow[row] * ws;
        #pragma unroll
        for (int j = 0; j < 2; ++j) {
          float a  = (float)acc[mi][2*j][r] * sc;
          float b2 = (float)acc[mi][2*j+1][r] * sc;
          int B = bn*128 + wc*64 + j*32;
          int h = B >> 7;
          int d = (B & 127) + 2*lrow;
          int i = d >> 1;
          float cc = cosb[(s << 6) + i], sn = sinb[(s << 6) + i];
          ushort2 o2;
          o2.x = f2bf(a*cc - b2*sn);
          o2.y = f2bf(a*sn + b2*cc);
          *(ushort2*)&dst[(((long)bidx*nh + h)*SEQ + s)*HDIM + d] = o2;
        }
      }
    }
  }
}

// ---------------- rope tables ----------------
__global__ __launch_bounds__(256) void k_ropetab(float* __restrict__ cosb, float* __restrict__ sinb) {
  int idx = blockIdx.x*256 + threadIdx.x;
  int s = idx >> 6, i = idx & 63;
  float e = (2.0f * (float)i) / 128.0f;
  float inv = 1.0f / powf(500000.0f, e);
  float f = (float)s * inv;
  cosb[idx] = cosf(f);
  sinb[idx] = sinf(f);
}

// ---------------- causal GQA flash attention, LDS-staged, causal-paired ----------------
__global__ __launch_bounds__(256) void k_attn(const u16* __restrict__ qb, const u16* __restrict__ kb,
                                              const u16* __restrict__ vt, float* __restrict__ ao) {
  int p = blockIdx.x, h = blockIdx.y, b = blockIdx.z;
  int t = threadIdx.x, lane = t & 63, wid = t >> 6;
  int lrow = lane & 15, l8 = lane >> 4;
  int x7 = lrow & 7;

  __shared__ u16 Ks[2][64*128] __attribute__((aligned(16)));
  __shared__ u16 Vs[2][128*64] __attribute__((aligned(16)));
  __shared__ u16 Ps[4][16][72] __attribute__((aligned(16)));

  const u16* kp = kb + ((long)(b*NKVH + (h >> 2)))*SEQ*HDIM;
  const u16* vp = vt + ((long)(b*NKVH + (h >> 2)))*HDIM*SEQ;

  auto stageK = [&](int buf, int j) {
    const u16* src = kp + (long)j*64*HDIM;
    #pragma unroll
    for (int i = 0; i < 4; ++i) {
      int r0 = wid*16 + i*4;
      int row = r0 + (lane >> 4);
      int cg = (lane & 15) ^ (row & 7);
      gload16(src + (long)row*HDIM + cg*8, &Ks[buf][r0*HDIM]);
    }
  };
  auto stageV = [&](int buf, int j) {
    #pragma unroll
    for (int i = 0; i < 4; ++i) {
      int r0 = wid*32 + i*8;
      int row = r0 + (lane >> 3);
      int cg = (lane & 7) ^ (row & 7);
      gload16(vp + (long)row*SEQ + j*64 + cg*8, &Vs[buf][r0*64]);
    }
  };

  for (int phase = 0; phase < 2; ++phase) {
    int qt = phase ? (15 - p) : p;
    int q0 = qt*64 + wid*16;
    const u16* qp = qb + (((long)(b*NHQ + h))*SEQ + q0)*HDIM;
    bf16x8 qf[4];
    #pragma unroll
    for (int ks = 0; ks < 4; ++ks) qf[ks] = *(const bf16x8*)&qp[lrow*HDIM + ks*32 + l8*8];
    f32x4 zero = {0.f, 0.f, 0.f, 0.f};
    f32x4 o[8];
    #pragma unroll
    for (int f = 0; f < 8; ++f) o[f] = zero;
    float m[4], ll[4];
    #pragma unroll
    for (int r = 0; r < 4; ++r) { m[r] = -1e30f; ll[r] = 0.f; }

    int nj = qt + 1;
    stageK(0, 0); stageV(0, 0);
    __syncthreads();
    int cur = 0;
    for (int j = 0; j < nj; ++j) {
      if (j + 1 < nj) { stageK(cur ^ 1, j + 1); stageV(cur ^ 1, j + 1); }
      const u16* Kc = Ks[cur];
      const u16* Vc = Vs[cur];
      f32x4 sc4[4];
      #pragma unroll
      for (int ni = 0; ni < 4; ++ni) sc4[ni] = zero;
      __builtin_amdgcn_s_setprio(1);
      #pragma unroll
      for (int ni = 0; ni < 4; ++ni) {
        int row = ni*16 + lrow;
        #pragma unroll
        for (int ks = 0; ks < 4; ++ks) {
          int cl = (ks*4 + l8) ^ x7;
          bf16x8 kfr = *(const bf16x8*)&Kc[row*HDIM + cl*8];
          sc4[ni] = __builtin_amdgcn_mfma_f32_16x16x32_bf16(qf[ks], kfr, sc4[ni], 0, 0, 0);
        }
      }
      __builtin_amdgcn_s_setprio(0);
      const float scale = 0.08838834764831845f;
      float pm[4] = {-1e30f, -1e30f, -1e30f, -1e30f};
      float pv[4][4];
      bool diag = (j == qt);
      #pragma unroll
      for (int ni = 0; ni < 4; ++ni) {
        int kv = j*64 + ni*16 + lrow;
        #pragma unroll
        for (int r = 0; r < 4; ++r) {
          int qr = q0 + l8*4 + r;
          float val = sc4[ni][r] * scale;
          if (diag && kv > qr) val = -1e30f;
          pv[ni][r] = val;
          pm[r] = fmaxf(pm[r], val);
        }
      }
      #pragma unroll
      for (int r = 0; r < 4; ++r) {
        #pragma unroll
        for (int off = 1; off < 16; off <<= 1) pm[r] = fmaxf(pm[r], __shfl_xor(pm[r], off));
      }
      float fr[4], rs[4];
      #pragma unroll
      for (int r = 0; r < 4; ++r) {
        float nm = fmaxf(m[r], pm[r]);
        fr[r] = __expf(m[r] - nm);
        m[r] = nm; rs[r] = 0.f;
      }
      #pragma unroll
      for (int ni = 0; ni < 4; ++ni)
        #pragma unroll
        for (int r = 0; r < 4; ++r) {
          float pe = __expf(pv[ni][r] - m[r]);
          pv[ni][r] = pe; rs[r] += pe;
        }
      #pragma unroll
      for (int r = 0; r < 4; ++r) {
        #pragma unroll
        for (int off = 1; off < 16; off <<= 1) rs[r] += __shfl_xor(rs[r], off);
        ll[r] = ll[r]*fr[r] + rs[r];
      }
      #pragma unroll
      for (int f = 0; f < 8; ++f) {
        o[f][0] *= fr[0]; o[f][1] *= fr[1]; o[f][2] *= fr[2]; o[f][3] *= fr[3];
      }
      #pragma unroll
      for (int ni = 0; ni < 4; ++ni)
        #pragma unroll
        for (int r = 0; r < 4; ++r)
          Ps[wid][l8*4 + r][ni*16 + lrow] = f2bf(pv[ni][r]);
      bf16x8 pf0 = *(const bf16x8*)&Ps[wid][lrow][l8*8];
      bf16x8 pf1 = *(const bf16x8*)&Ps[wid][lrow][32 + l8*8];
      __builtin_amdgcn_s_setprio(1);
      #pragma unroll
      for (int f = 0; f < 8; ++f) {
        int d = f*16 + lrow;
        bf16x8 v0 = *(const bf16x8*)&Vc[d*64 + ((l8) ^ x7)*8];
        bf16x8 v1 = *(const bf16x8*)&Vc[d*64 + ((4 + l8) ^ x7)*8];
        o[f] = __builtin_amdgcn_mfma_f32_16x16x32_bf16(pf0, v0, o[f], 0, 0, 0);
        o[f] = __builtin_amdgcn_mfma_f32_16x16x32_bf16(pf1, v1, o[f], 0, 0, 0);
      }
      __builtin_amdgcn_s_setprio(0);
      __syncthreads();
      cur ^= 1;
    }
    float invl[4];
    #pragma unroll
    for (int r = 0; r < 4; ++r) invl[r] = 1.0f / ll[r];
    #pragma unroll
    for (int f = 0; f < 8; ++f)
      #pragma unroll
      for (int r = 0; r < 4; ++r) {
        long row = (long)b*SEQ + q0 + l8*4 + r;
        ao[row*HID + h*HDIM + f*16 + lrow] = o[f][r] * invl[r];
      }
    __syncthreads();
  }
}

// ---------------- fused rmsnorm + act quant -> int8 ----------------
__global__ __launch_bounds__(256) void k_rmsq8(const float* __restrict__ x, const float* __restrict__ w,
                                               char* __restrict__ yq, float* __restrict__ ys) {
  long row = blockIdx.x;
  const float4* xr = (const float4*)(x + row*HID);
  const float4* wr = (const float4*)w;
  float4 v[4];
  float ss = 0.f;
  #pragma unroll
  for (int j = 0; j < 4; ++j) {
    v[j] = xr[j*256 + threadIdx.x];
    ss += v[j].x*v[j].x + v[j].y*v[j].y + v[j].z*v[j].z + v[j].w*v[j].w;
  }
  #pragma unroll
  for (int off = 1; off < 64; off <<= 1) ss += __shfl_xor(ss, off);
  __shared__ float red[4];
  if ((threadIdx.x & 63) == 0) red[threadIdx.x >> 6] = ss;
  __syncthreads();
  ss = red[0] + red[1] + red[2] + red[3];
  __syncthreads();
  float rn = rsqrtf(ss / (float)HID + 1e-6f);
  float4 y[4];
  float am = 0.f;
  #pragma unroll
  for (int j = 0; j < 4; ++j) {
    float4 wv = wr[j*256 + threadIdx.x];
    y[j].x = v[j].x * rn * wv.x; y[j].y = v[j].y * rn * wv.y;
    y[j].z = v[j].z * rn * wv.z; y[j].w = v[j].w * rn * wv.w;
    am = fmaxf(am, fmaxf(fmaxf(fabsf(y[j].x), fabsf(y[j].y)), fmaxf(fabsf(y[j].z), fabsf(y[j].w))));
  }
  #pragma unroll
  for (int off = 1; off < 64; off <<= 1) am = fmaxf(am, __shfl_xor(am, off));
  if ((threadIdx.x & 63) == 0) red[threadIdx.x >> 6] = am;
  __syncthreads();
  am = fmaxf(fmaxf(red[0], red[1]), fmaxf(red[2], red[3]));
  float amc = fmaxf(am, 1e-5f);
  float s = 127.0f / amc;
  int* oq = (int*)(yq + row*HID);
  #pragma unroll
  for (int j = 0; j < 4; ++j)
    oq[j*256 + threadIdx.x] = pack4i8(y[j].x, y[j].y, y[j].z, y[j].w, s, -128.f, 127.f);
  if (threadIdx.x == 0) ys[row] = amc / 127.0f;
}

extern "C" void kernel_launch(void* const* d_in, const int* in_sizes, int n_in,
                              void* d_out, int out_size, void* d_ws, size_t ws_size,
                              hipStream_t stream) {
  const float* hs    = (const float*)d_in[0];
  const float* w_q   = (const float*)d_in[2];
  const float* w_k   = (const float*)d_in[3];
  const float* w_v   = (const float*)d_in[4];
  const float* w_o   = (const float*)d_in[5];
  const float* subln = (const float*)d_in[6];

  char* ws = (char*)d_ws;
  char*  wqq = (char*)(ws + 0L);                  // 16777216 (i8, rows perm'd)
  char*  wqk = (char*)(ws + 16777216L);           // 4194304  (i8, rows perm'd)
  char*  wqv = (char*)(ws + 20971520L);           // 4194304
  char*  wqo = (char*)(ws + 25165824L);           // 16777216
  char*  xq  = (char*)(ws + 41943040L);           // 8388608
  float* ao  = (float*)(ws + 50331648L);          // 33554432 (fp32 attention out)
  char*  yq  = (char*)(ws + 83886080L);           // 8388608  (i8 rmsnorm out)
  u16*   qb  = (u16*)(ws + 92274688L);            // 16777216 (bf16 rope'd Q)
  u16*   kb  = (u16*)(ws + 109051904L);           // 4194304  (bf16 rope'd K)
  u16*   vtb = (u16*)(ws + 113246208L);           // 4194304  (bf16 V^T)
  float* cosb= (float*)(ws + 117440512L);         // 262144
  float* sinb= (float*)(ws + 117702656L);         // 262144
  float* xs  = (float*)(ws + 117964800L);         // 8192
  float* ys  = (float*)(ws + 117972992L);         // 8192
  float* wsc = (float*)(ws + 117981184L);         // 64
  float* par = (float*)(ws + 117981248L);         // 16384
  float* out = (float*)d_out;

  // 1. weight scales (merged)
  k_abssum4<<<2560, 256, 0, stream>>>(w_q, w_k, w_v, w_o, par);
  k_wscale<<<1, 256, 0, stream>>>(par, wsc);

  // 2. quantize weights (merged, ternary i8; Q/K rows perm'd for lane-local RoPE pairs)
  k_quantw8_all<<<40960, 256, 0, stream>>>(w_q, w_k, w_v, w_o, wqq, wqk, wqv, wqo, wsc);
  k_ropetab<<<256, 256, 0, stream>>>(cosb, sinb);
  k_actq8<<<NROWS, 256, 0, stream>>>(hs, xq, xs);

  // 3. merged Q/K/V i8 GEMM, counted-vmcnt pipeline, fused RoPE + V-transpose epilogues
  k_gemm8_qkv<<<768, 256, 0, stream>>>(xq, wqq, wqk, wqv, qb, kb, vtb, xs, wsc, cosb, sinb);

  // 4. attention
  k_attn<<<dim3(8, 32, 2), 256, 0, stream>>>(qb, kb, vtb, ao);

  // 5. rmsnorm + act quant
  k_rmsq8<<<NROWS, 256, 0, stream>>>(ao, subln, yq, ys);

  // 6. output i8 GEMM (64x128 tile, counted-vmcnt pipeline)
  k_gemm8<<<1024, 256, 0, stream>>>(yq, wqo, out, ys, wsc, 3, NROWS, 4096, 4096);
}

// Round 7
// 245.770 us; speedup vs baseline: 3.2622x; 1.1271x over previous
//
#include <hip/hip_runtime.h>
#include <hip/hip_bf16.h>
#include <cstdint>

typedef unsigned short u16;
typedef __bf16 bf16x8 __attribute__((ext_vector_type(8)));
typedef float f32x4 __attribute__((ext_vector_type(4)));
typedef int i32x4 __attribute__((ext_vector_type(4)));

#define SEQ 1024
#define HID 4096
#define NHQ 32
#define NKVH 8
#define HDIM 128
#define NB 2
#define NROWS (NB*SEQ)

static __device__ __forceinline__ u16 f2bf(float x) {
  __hip_bfloat16 h = __float2bfloat16(x);
  return *reinterpret_cast<u16*>(&h);
}

static __device__ __forceinline__ void gload16(const void* g, void* l) {
  __builtin_amdgcn_global_load_lds((__attribute__((address_space(1))) void*)(void*)g,
                                   (__attribute__((address_space(3))) void*)l, 16, 0, 0);
}

static __device__ __forceinline__ int pack4i8(float a, float b, float c, float d,
                                              float s, float lo, float hi) {
  int x0 = (int)fminf(fmaxf(rintf(a*s), lo), hi);
  int x1 = (int)fminf(fmaxf(rintf(b*s), lo), hi);
  int x2 = (int)fminf(fmaxf(rintf(c*s), lo), hi);
  int x3 = (int)fminf(fmaxf(rintf(d*s), lo), hi);
  return (x0 & 255) | ((x1 & 255) << 8) | ((x2 & 255) << 16) | ((x3 & 255) << 24);
}

// ---------------- merged weight abs-sum (pass 1): 2560 blocks ----------------
__global__ __launch_bounds__(256) void k_abssum4(const float* __restrict__ wq_, const float* __restrict__ wk_,
                                                 const float* __restrict__ wv_, const float* __restrict__ wo_,
                                                 float* __restrict__ partial) {
  int bx = blockIdx.x;
  const float* w; long n4; int pbase, lb, nb;
  if (bx < 1024)      { w = wq_; n4 = 4194304; pbase = 0;    lb = bx;        nb = 1024; }
  else if (bx < 1280) { w = wk_; n4 = 1048576; pbase = 1024; lb = bx - 1024; nb = 256; }
  else if (bx < 1536) { w = wv_; n4 = 1048576; pbase = 1280; lb = bx - 1280; nb = 256; }
  else                { w = wo_; n4 = 4194304; pbase = 1536; lb = bx - 1536; nb = 1024; }
  float s = 0.f;
  long stride = (long)nb * 256;
  const float4* w4 = (const float4*)w;
  for (long j = (long)lb*256 + threadIdx.x; j < n4; j += stride) {
    float4 v = w4[j];
    s += fabsf(v.x) + fabsf(v.y) + fabsf(v.z) + fabsf(v.w);
  }
  #pragma unroll
  for (int off = 1; off < 64; off <<= 1) s += __shfl_xor(s, off);
  __shared__ float red[4];
  if ((threadIdx.x & 63) == 0) red[threadIdx.x >> 6] = s;
  __syncthreads();
  if (threadIdx.x == 0) partial[pbase + lb] = red[0] + red[1] + red[2] + red[3];
}

// ---------------- weight scales (pass 2) ----------------
__global__ __launch_bounds__(256) void k_wscale(const float* __restrict__ partial,
                                                float* __restrict__ wsc) {
  __shared__ float red[4];
  const float nelem[4] = {16777216.f, 4194304.f, 4194304.f, 16777216.f};
  const int pbase[4] = {0, 1024, 1280, 1536};
  const int pcnt[4]  = {1024, 256, 256, 1024};
  for (int wi = 0; wi < 4; ++wi) {
    float s = 0.f;
    for (int j = threadIdx.x; j < pcnt[wi]; j += 256) s += partial[pbase[wi] + j];
    #pragma unroll
    for (int off = 1; off < 64; off <<= 1) s += __shfl_xor(s, off);
    if ((threadIdx.x & 63) == 0) red[threadIdx.x >> 6] = s;
    __syncthreads();
    if (threadIdx.x == 0) wsc[wi] = fmaxf((red[0]+red[1]+red[2]+red[3]) / nelem[wi], 1e-5f);
    __syncthreads();
  }
}

// ---------------- merged ternary weight quantize -> int8 (40960 blocks) ----------------
__global__ __launch_bounds__(256) void k_quantw8_all(const float* __restrict__ wq_, const float* __restrict__ wk_,
                                                     const float* __restrict__ wv_, const float* __restrict__ wo_,
                                                     char* __restrict__ oq_, char* __restrict__ ok_,
                                                     char* __restrict__ ov_, char* __restrict__ oo_,
                                                     const float* __restrict__ wsc) {
  int bx = blockIdx.x;
  const float* src; char* dst; int idx; long base;
  if (bx < 16384)      { src = wq_; dst = oq_; idx = 0; base = bx; }
  else if (bx < 20480) { src = wk_; dst = ok_; idx = 1; base = bx - 16384; }
  else if (bx < 24576) { src = wv_; dst = ov_; idx = 2; base = bx - 20480; }
  else                 { src = wo_; dst = oo_; idx = 3; base = bx - 24576; }
  long j = base*256 + threadIdx.x;        // float4 index; 1024 per weight row
  long oj = j;
  if (idx <= 1) {
    long row = j >> 10;
    int u = (int)(row & 31);
    long prow = (row & ~31L) | (long)((u >> 1) | ((u & 1) << 4));
    oj = (prow << 10) | (j & 1023);
  }
  float inv = 1.0f / wsc[idx];
  float4 v = ((const float4*)src)[j];
  ((int*)dst)[oj] = pack4i8(v.x, v.y, v.z, v.w, inv, -1.f, 1.f);
}

// ---------------- per-row activation quantize (hidden) -> int8 ----------------
__global__ __launch_bounds__(256) void k_actq8(const float* __restrict__ x, char* __restrict__ xq,
                                               float* __restrict__ xs) {
  long row = blockIdx.x;
  const float4* xr = (const float4*)(x + row*HID);
  float4 v[4];
  float am = 0.f;
  #pragma unroll
  for (int j = 0; j < 4; ++j) {
    v[j] = xr[j*256 + threadIdx.x];
    am = fmaxf(am, fmaxf(fmaxf(fabsf(v[j].x), fabsf(v[j].y)), fmaxf(fabsf(v[j].z), fabsf(v[j].w))));
  }
  #pragma unroll
  for (int off = 1; off < 64; off <<= 1) am = fmaxf(am, __shfl_xor(am, off));
  __shared__ float red[4];
  if ((threadIdx.x & 63) == 0) red[threadIdx.x >> 6] = am;
  __syncthreads();
  am = fmaxf(fmaxf(red[0], red[1]), fmaxf(red[2], red[3]));
  float amc = fmaxf(am, 1e-5f);
  float s = 127.0f / amc;
  int* oq = (int*)(xq + row*HID);
  #pragma unroll
  for (int j = 0; j < 4; ++j)
    oq[j*256 + threadIdx.x] = pack4i8(v[j].x, v[j].y, v[j].z, v[j].w, s, -128.f, 127.f);
  if (threadIdx.x == 0) xs[row] = amc / 127.0f;
}

// ---------------- i8 O-GEMM: 128x128 tile, 2 waves (64x128 each), 1 barrier/step ----------------
__global__ __launch_bounds__(128, 2) void k_gemm8(const char* __restrict__ A, const char* __restrict__ W,
                                                  float* __restrict__ C, const float* __restrict__ arow,
                                                  const float* __restrict__ wsc, int widx,
                                                  int M, int N, int K) {
  __shared__ char As[3][128*64] __attribute__((aligned(16)));
  __shared__ char Ws_[3][128*64] __attribute__((aligned(16)));
  int t = threadIdx.x;
  // supertile XCD map over 512 blocks: xcd owns 8bm x 8bn square
  int bid = blockIdx.x;
  int xcd = bid & 7, w = bid >> 3;                 // w in 0..63
  int bm = ((xcd & 1) << 3) + (w >> 3);            // 0..15
  int bn = ((xcd >> 1) << 3) + (w & 7);            // 0..31
  const char* Ab = A + (long)bm*128*K;
  const char* Wb = W + (long)bn*128*K;
  int lane = t & 63, wid = t >> 6;
  int lrow = lane & 15, l8 = lane >> 4;
  int ch0 = (l8 ^ ((lrow >> 1) & 3)) * 16;
  i32x4 zero = {0, 0, 0, 0};
  i32x4 acc[4][8];
  #pragma unroll
  for (int mi = 0; mi < 4; ++mi)
    #pragma unroll
    for (int ni = 0; ni < 8; ++ni) acc[mi][ni] = zero;

  auto stage = [&](int buf, int kt) {              // 8 VMEM ops per thread
    #pragma unroll
    for (int i = 0; i < 4; ++i) {
      int c = t + 128*i;
      int row = c >> 2;
      int ci = ((c & 3) ^ ((row >> 1) & 3)) * 16;  // pre-swizzled global chunk (rule #21)
      gload16(Ab + (long)row*K + kt*64 + ci, &As[buf][c*16]);
      gload16(Wb + (long)row*K + kt*64 + ci, &Ws_[buf][c*16]);
    }
  };

  int nk = K >> 6;                                 // 64
  stage(0, 0); stage(1, 1);
  asm volatile("s_waitcnt vmcnt(8)" ::: "memory");
  __builtin_amdgcn_sched_barrier(0);
  __builtin_amdgcn_s_barrier();
  __builtin_amdgcn_sched_barrier(0);
  for (int kt = 0; kt < nk; ++kt) {
    int cur = kt % 3;
    i32x4 af[4], bfr[8];
    #pragma unroll
    for (int mi = 0; mi < 4; ++mi) af[mi] = *(const i32x4*)&As[cur][(wid*64 + mi*16 + lrow)*64 + ch0];
    #pragma unroll
    for (int ni = 0; ni < 8; ++ni) bfr[ni] = *(const i32x4*)&Ws_[cur][(ni*16 + lrow)*64 + ch0];
    if (kt + 2 < nk) stage((kt + 2) % 3, kt + 2);
    __builtin_amdgcn_s_setprio(1);
    #pragma unroll
    for (int mi = 0; mi < 4; ++mi)
      #pragma unroll
      for (int ni = 0; ni < 8; ++ni)
        acc[mi][ni] = __builtin_amdgcn_mfma_i32_16x16x64_i8(af[mi], bfr[ni], acc[mi][ni], 0, 0, 0);
    __builtin_amdgcn_s_setprio(0);
    if (kt + 2 < nk)      asm volatile("s_waitcnt vmcnt(8)" ::: "memory");
    else if (kt + 1 < nk) asm volatile("s_waitcnt vmcnt(0)" ::: "memory");
    if (kt + 1 < nk) {
      __builtin_amdgcn_sched_barrier(0);
      __builtin_amdgcn_s_barrier();
      __builtin_amdgcn_sched_barrier(0);
    }
  }
  float ws = wsc[widx];
  #pragma unroll
  for (int mi = 0; mi < 4; ++mi)
    #pragma unroll
    for (int r = 0; r < 4; ++r) {
      int row = bm*128 + wid*64 + mi*16 + l8*4 + r;
      float sc = arow[row] * ws;
      #pragma unroll
      for (int ni = 0; ni < 8; ++ni) {
        int col = bn*128 + ni*16 + lrow;
        C[(long)row*N + col] = (float)acc[mi][ni][r] * sc;
      }
    }
}

// ---------------- merged i8 QKV GEMM: 128x128, 2 waves, 1 barrier/step, fused RoPE ----------------
__global__ __launch_bounds__(128, 2) void k_gemm8_qkv(const char* __restrict__ A,
    const char* __restrict__ Wq, const char* __restrict__ Wk, const char* __restrict__ Wv,
    u16* __restrict__ Qb, u16* __restrict__ Kb, u16* __restrict__ Vt,
    const float* __restrict__ arow, const float* __restrict__ wsc,
    const float* __restrict__ cosb, const float* __restrict__ sinb) {
  const int K = 4096;
  int bid = blockIdx.x;
  int xcd = bid & 7, w = bid >> 3;                 // w in 0..95
  int kind, bm, bn;
  const char* W;
  if (w < 64)      { kind = 0; bm = ((xcd & 1) << 3) + (w >> 3); bn = ((xcd >> 1) << 3) + (w & 7); W = Wq; }
  else if (w < 80) { int u = w - 64; kind = 1; bm = (xcd << 1) + (u >> 3); bn = u & 7; W = Wk; }
  else             { int u = w - 80; kind = 2; bm = (xcd << 1) + (u >> 3); bn = u & 7; W = Wv; }

  __shared__ char As[3][128*64] __attribute__((aligned(16)));
  __shared__ char Ws_[3][128*64] __attribute__((aligned(16)));
  int t = threadIdx.x;
  const char* Ab = A + (long)bm*128*K;
  const char* Wb = W + (long)bn*128*K;
  int lane = t & 63, wid = t >> 6;
  int lrow = lane & 15, l8 = lane >> 4;
  int ch0 = (l8 ^ ((lrow >> 1) & 3)) * 16;
  i32x4 zero = {0, 0, 0, 0};
  i32x4 acc[4][8];
  #pragma unroll
  for (int mi = 0; mi < 4; ++mi)
    #pragma unroll
    for (int ni = 0; ni < 8; ++ni) acc[mi][ni] = zero;

  auto stage = [&](int buf, int kt) {              // 8 VMEM ops per thread
    #pragma unroll
    for (int i = 0; i < 4; ++i) {
      int c = t + 128*i;
      int row = c >> 2;
      int ci = ((c & 3) ^ ((row >> 1) & 3)) * 16;
      gload16(Ab + (long)row*K + kt*64 + ci, &As[buf][c*16]);
      gload16(Wb + (long)row*K + kt*64 + ci, &Ws_[buf][c*16]);
    }
  };

  int nk = K >> 6;                                 // 64
  stage(0, 0); stage(1, 1);
  asm volatile("s_waitcnt vmcnt(8)" ::: "memory");
  __builtin_amdgcn_sched_barrier(0);
  __builtin_amdgcn_s_barrier();
  __builtin_amdgcn_sched_barrier(0);
  for (int kt = 0; kt < nk; ++kt) {
    int cur = kt % 3;
    i32x4 af[4], bfr[8];
    #pragma unroll
    for (int mi = 0; mi < 4; ++mi) af[mi] = *(const i32x4*)&As[cur][(wid*64 + mi*16 + lrow)*64 + ch0];
    #pragma unroll
    for (int ni = 0; ni < 8; ++ni) bfr[ni] = *(const i32x4*)&Ws_[cur][(ni*16 + lrow)*64 + ch0];
    if (kt + 2 < nk) stage((kt + 2) % 3, kt + 2);
    __builtin_amdgcn_s_setprio(1);
    #pragma unroll
    for (int mi = 0; mi < 4; ++mi)
      #pragma unroll
      for (int ni = 0; ni < 8; ++ni)
        acc[mi][ni] = __builtin_amdgcn_mfma_i32_16x16x64_i8(af[mi], bfr[ni], acc[mi][ni], 0, 0, 0);
    __builtin_amdgcn_s_setprio(0);
    if (kt + 2 < nk)      asm volatile("s_waitcnt vmcnt(8)" ::: "memory");
    else if (kt + 1 < nk) asm volatile("s_waitcnt vmcnt(0)" ::: "memory");
    if (kt + 1 < nk) {
      __builtin_amdgcn_sched_barrier(0);
      __builtin_amdgcn_s_barrier();
      __builtin_amdgcn_sched_barrier(0);
    }
  }

  if (kind == 2) {
    float ws = wsc[2];
    #pragma unroll
    for (int mi = 0; mi < 4; ++mi) {
      int row0 = bm*128 + wid*64 + mi*16 + l8*4;
      int bidx = row0 >> 10, s0 = row0 & 1023;
      #pragma unroll
      for (int ni = 0; ni < 8; ++ni) {
        int col = bn*128 + ni*16 + lrow;
        int hkv = col >> 7, d = col & 127;
        ushort4 o4;
        o4.x = f2bf((float)acc[mi][ni][0] * arow[row0+0] * ws);
        o4.y = f2bf((float)acc[mi][ni][1] * arow[row0+1] * ws);
        o4.z = f2bf((float)acc[mi][ni][2] * arow[row0+2] * ws);
        o4.w = f2bf((float)acc[mi][ni][3] * arow[row0+3] * ws);
        *(ushort4*)&Vt[(((long)bidx*NKVH + hkv)*HDIM + d)*SEQ + s0] = o4;
      }
    }
  } else {
    // Weight rows permuted at quant: (acc[mi][2j], acc[mi][2j+1]) are the RoPE pair
    // (B+2*lrow, B+2*lrow+1), B = bn*128 + j*32 — lane-local, no shfl.
    float ws = wsc[kind];
    u16* dst = kind ? Kb : Qb;
    int nh = kind ? NKVH : NHQ;
    #pragma unroll
    for (int mi = 0; mi < 4; ++mi) {
      #pragma unroll
      for (int r = 0; r < 4; ++r) {
        int row = bm*128 + wid*64 + mi*16 + l8*4 + r;
        int bidx = row >> 10, s = row & 1023;
        float sc = arow[row] * ws;
        #pragma unroll
        for (int j = 0; j < 4; ++j) {
          float a  = (float)acc[mi][2*j][r] * sc;
          float b2 = (float)acc[mi][2*j+1][r] * sc;
          int B = bn*128 + j*32;
          int h = B >> 7;
          int d = (B & 127) + 2*lrow;
          int i = d >> 1;
          float cc = cosb[(s << 6) + i], sn = sinb[(s << 6) + i];
          ushort2 o2;
          o2.x = f2bf(a*cc - b2*sn);
          o2.y = f2bf(a*sn + b2*cc);
          *(ushort2*)&dst[(((long)bidx*nh + h)*SEQ + s)*HDIM + d] = o2;
        }
      }
    }
  }
}

// ---------------- rope tables ----------------
__global__ __launch_bounds__(256) void k_ropetab(float* __restrict__ cosb, float* __restrict__ sinb) {
  int idx = blockIdx.x*256 + threadIdx.x;
  int s = idx >> 6, i = idx & 63;
  float e = (2.0f * (float)i) / 128.0f;
  float inv = 1.0f / powf(500000.0f, e);
  float f = (float)s * inv;
  cosb[idx] = cosf(f);
  sinb[idx] = sinf(f);
}

// ---------------- causal GQA flash attention, LDS-staged, causal-paired ----------------
__global__ __launch_bounds__(256) void k_attn(const u16* __restrict__ qb, const u16* __restrict__ kb,
                                              const u16* __restrict__ vt, float* __restrict__ ao) {
  int p = blockIdx.x, h = blockIdx.y, b = blockIdx.z;
  int t = threadIdx.x, lane = t & 63, wid = t >> 6;
  int lrow = lane & 15, l8 = lane >> 4;
  int x7 = lrow & 7;

  __shared__ u16 Ks[2][64*128] __attribute__((aligned(16)));
  __shared__ u16 Vs[2][128*64] __attribute__((aligned(16)));
  __shared__ u16 Ps[4][16][72] __attribute__((aligned(16)));

  const u16* kp = kb + ((long)(b*NKVH + (h >> 2)))*SEQ*HDIM;
  const u16* vp = vt + ((long)(b*NKVH + (h >> 2)))*HDIM*SEQ;

  auto stageK = [&](int buf, int j) {
    const u16* src = kp + (long)j*64*HDIM;
    #pragma unroll
    for (int i = 0; i < 4; ++i) {
      int r0 = wid*16 + i*4;
      int row = r0 + (lane >> 4);
      int cg = (lane & 15) ^ (row & 7);
      gload16(src + (long)row*HDIM + cg*8, &Ks[buf][r0*HDIM]);
    }
  };
  auto stageV = [&](int buf, int j) {
    #pragma unroll
    for (int i = 0; i < 4; ++i) {
      int r0 = wid*32 + i*8;
      int row = r0 + (lane >> 3);
      int cg = (lane & 7) ^ (row & 7);
      gload16(vp + (long)row*SEQ + j*64 + cg*8, &Vs[buf][r0*64]);
    }
  };

  for (int phase = 0; phase < 2; ++phase) {
    int qt = phase ? (15 - p) : p;
    int q0 = qt*64 + wid*16;
    const u16* qp = qb + (((long)(b*NHQ + h))*SEQ + q0)*HDIM;
    bf16x8 qf[4];
    #pragma unroll
    for (int ks = 0; ks < 4; ++ks) qf[ks] = *(const bf16x8*)&qp[lrow*HDIM + ks*32 + l8*8];
    f32x4 zero = {0.f, 0.f, 0.f, 0.f};
    f32x4 o[8];
    #pragma unroll
    for (int f = 0; f < 8; ++f) o[f] = zero;
    float m[4], ll[4];
    #pragma unroll
    for (int r = 0; r < 4; ++r) { m[r] = -1e30f; ll[r] = 0.f; }

    int nj = qt + 1;
    stageK(0, 0); stageV(0, 0);
    __syncthreads();
    int cur = 0;
    for (int j = 0; j < nj; ++j) {
      if (j + 1 < nj) { stageK(cur ^ 1, j + 1); stageV(cur ^ 1, j + 1); }
      const u16* Kc = Ks[cur];
      const u16* Vc = Vs[cur];
      f32x4 sc4[4];
      #pragma unroll
      for (int ni = 0; ni < 4; ++ni) sc4[ni] = zero;
      __builtin_amdgcn_s_setprio(1);
      #pragma unroll
      for (int ni = 0; ni < 4; ++ni) {
        int row = ni*16 + lrow;
        #pragma unroll
        for (int ks = 0; ks < 4; ++ks) {
          int cl = (ks*4 + l8) ^ x7;
          bf16x8 kfr = *(const bf16x8*)&Kc[row*HDIM + cl*8];
          sc4[ni] = __builtin_amdgcn_mfma_f32_16x16x32_bf16(qf[ks], kfr, sc4[ni], 0, 0, 0);
        }
      }
      __builtin_amdgcn_s_setprio(0);
      const float scale = 0.08838834764831845f;
      float pm[4] = {-1e30f, -1e30f, -1e30f, -1e30f};
      float pv[4][4];
      bool diag = (j == qt);
      #pragma unroll
      for (int ni = 0; ni < 4; ++ni) {
        int kv = j*64 + ni*16 + lrow;
        #pragma unroll
        for (int r = 0; r < 4; ++r) {
          int qr = q0 + l8*4 + r;
          float val = sc4[ni][r] * scale;
          if (diag && kv > qr) val = -1e30f;
          pv[ni][r] = val;
          pm[r] = fmaxf(pm[r], val);
        }
      }
      #pragma unroll
      for (int r = 0; r < 4; ++r) {
        #pragma unroll
        for (int off = 1; off < 16; off <<= 1) pm[r] = fmaxf(pm[r], __shfl_xor(pm[r], off));
      }
      float fr[4], rs[4];
      #pragma unroll
      for (int r = 0; r < 4; ++r) {
        float nm = fmaxf(m[r], pm[r]);
        fr[r] = __expf(m[r] - nm);
        m[r] = nm; rs[r] = 0.f;
      }
      #pragma unroll
      for (int ni = 0; ni < 4; ++ni)
        #pragma unroll
        for (int r = 0; r < 4; ++r) {
          float pe = __expf(pv[ni][r] - m[r]);
          pv[ni][r] = pe; rs[r] += pe;
        }
      #pragma unroll
      for (int r = 0; r < 4; ++r) {
        #pragma unroll
        for (int off = 1; off < 16; off <<= 1) rs[r] += __shfl_xor(rs[r], off);
        ll[r] = ll[r]*fr[r] + rs[r];
      }
      #pragma unroll
      for (int f = 0; f < 8; ++f) {
        o[f][0] *= fr[0]; o[f][1] *= fr[1]; o[f][2] *= fr[2]; o[f][3] *= fr[3];
      }
      #pragma unroll
      for (int ni = 0; ni < 4; ++ni)
        #pragma unroll
        for (int r = 0; r < 4; ++r)
          Ps[wid][l8*4 + r][ni*16 + lrow] = f2bf(pv[ni][r]);
      bf16x8 pf0 = *(const bf16x8*)&Ps[wid][lrow][l8*8];
      bf16x8 pf1 = *(const bf16x8*)&Ps[wid][lrow][32 + l8*8];
      __builtin_amdgcn_s_setprio(1);
      #pragma unroll
      for (int f = 0; f < 8; ++f) {
        int d = f*16 + lrow;
        bf16x8 v0 = *(const bf16x8*)&Vc[d*64 + ((l8) ^ x7)*8];
        bf16x8 v1 = *(const bf16x8*)&Vc[d*64 + ((4 + l8) ^ x7)*8];
        o[f] = __builtin_amdgcn_mfma_f32_16x16x32_bf16(pf0, v0, o[f], 0, 0, 0);
        o[f] = __builtin_amdgcn_mfma_f32_16x16x32_bf16(pf1, v1, o[f], 0, 0, 0);
      }
      __builtin_amdgcn_s_setprio(0);
      __syncthreads();
      cur ^= 1;
    }
    float invl[4];
    #pragma unroll
    for (int r = 0; r < 4; ++r) invl[r] = 1.0f / ll[r];
    #pragma unroll
    for (int f = 0; f < 8; ++f)
      #pragma unroll
      for (int r = 0; r < 4; ++r) {
        long row = (long)b*SEQ + q0 + l8*4 + r;
        ao[row*HID + h*HDIM + f*16 + lrow] = o[f][r] * invl[r];
      }
    __syncthreads();
  }
}

// ---------------- fused rmsnorm + act quant -> int8 ----------------
__global__ __launch_bounds__(256) void k_rmsq8(const float* __restrict__ x, const float* __restrict__ w,
                                               char* __restrict__ yq, float* __restrict__ ys) {
  long row = blockIdx.x;
  const float4* xr = (const float4*)(x + row*HID);
  const float4* wr = (const float4*)w;
  float4 v[4];
  float ss = 0.f;
  #pragma unroll
  for (int j = 0; j < 4; ++j) {
    v[j] = xr[j*256 + threadIdx.x];
    ss += v[j].x*v[j].x + v[j].y*v[j].y + v[j].z*v[j].z + v[j].w*v[j].w;
  }
  #pragma unroll
  for (int off = 1; off < 64; off <<= 1) ss += __shfl_xor(ss, off);
  __shared__ float red[4];
  if ((threadIdx.x & 63) == 0) red[threadIdx.x >> 6] = ss;
  __syncthreads();
  ss = red[0] + red[1] + red[2] + red[3];
  __syncthreads();
  float rn = rsqrtf(ss / (float)HID + 1e-6f);
  float4 y[4];
  float am = 0.f;
  #pragma unroll
  for (int j = 0; j < 4; ++j) {
    float4 wv = wr[j*256 + threadIdx.x];
    y[j].x = v[j].x * rn * wv.x; y[j].y = v[j].y * rn * wv.y;
    y[j].z = v[j].z * rn * wv.z; y[j].w = v[j].w * rn * wv.w;
    am = fmaxf(am, fmaxf(fmaxf(fabsf(y[j].x), fabsf(y[j].y)), fmaxf(fabsf(y[j].z), fabsf(y[j].w))));
  }
  #pragma unroll
  for (int off = 1; off < 64; off <<= 1) am = fmaxf(am, __shfl_xor(am, off));
  if ((threadIdx.x & 63) == 0) red[threadIdx.x >> 6] = am;
  __syncthreads();
  am = fmaxf(fmaxf(red[0], red[1]), fmaxf(red[2], red[3]));
  float amc = fmaxf(am, 1e-5f);
  float s = 127.0f / amc;
  int* oq = (int*)(yq + row*HID);
  #pragma unroll
  for (int j = 0; j < 4; ++j)
    oq[j*256 + threadIdx.x] = pack4i8(y[j].x, y[j].y, y[j].z, y[j].w, s, -128.f, 127.f);
  if (threadIdx.x == 0) ys[row] = amc / 127.0f;
}

extern "C" void kernel_launch(void* const* d_in, const int* in_sizes, int n_in,
                              void* d_out, int out_size, void* d_ws, size_t ws_size,
                              hipStream_t stream) {
  const float* hs    = (const float*)d_in[0];
  const float* w_q   = (const float*)d_in[2];
  const float* w_k   = (const float*)d_in[3];
  const float* w_v   = (const float*)d_in[4];
  const float* w_o   = (const float*)d_in[5];
  const float* subln = (const float*)d_in[6];

  char* ws = (char*)d_ws;
  char*  wqq = (char*)(ws + 0L);                  // 16777216 (i8, rows perm'd)
  char*  wqk = (char*)(ws + 16777216L);           // 4194304  (i8, rows perm'd)
  char*  wqv = (char*)(ws + 20971520L);           // 4194304
  char*  wqo = (char*)(ws + 25165824L);           // 16777216
  char*  xq  = (char*)(ws + 41943040L);           // 8388608
  float* ao  = (float*)(ws + 50331648L);          // 33554432 (fp32 attention out)
  char*  yq  = (char*)(ws + 83886080L);           // 8388608  (i8 rmsnorm out)
  u16*   qb  = (u16*)(ws + 92274688L);            // 16777216 (bf16 rope'd Q)
  u16*   kb  = (u16*)(ws + 109051904L);           // 4194304  (bf16 rope'd K)
  u16*   vtb = (u16*)(ws + 113246208L);           // 4194304  (bf16 V^T)
  float* cosb= (float*)(ws + 117440512L);         // 262144
  float* sinb= (float*)(ws + 117702656L);         // 262144
  float* xs  = (float*)(ws + 117964800L);         // 8192
  float* ys  = (float*)(ws + 117972992L);         // 8192
  float* wsc = (float*)(ws + 117981184L);         // 64
  float* par = (float*)(ws + 117981248L);         // 16384
  float* out = (float*)d_out;

  // 1. weight scales (merged)
  k_abssum4<<<2560, 256, 0, stream>>>(w_q, w_k, w_v, w_o, par);
  k_wscale<<<1, 256, 0, stream>>>(par, wsc);

  // 2. quantize weights (merged, ternary i8; Q/K rows perm'd for lane-local RoPE pairs)
  k_quantw8_all<<<40960, 256, 0, stream>>>(w_q, w_k, w_v, w_o, wqq, wqk, wqv, wqo, wsc);
  k_ropetab<<<256, 256, 0, stream>>>(cosb, sinb);
  k_actq8<<<NROWS, 256, 0, stream>>>(hs, xq, xs);

  // 3. merged Q/K/V i8 GEMM (2-wave, single-barrier pipeline), fused RoPE + V-transpose
  k_gemm8_qkv<<<768, 128, 0, stream>>>(xq, wqq, wqk, wqv, qb, kb, vtb, xs, wsc, cosb, sinb);

  // 4. attention
  k_attn<<<dim3(8, 32, 2), 256, 0, stream>>>(qb, kb, vtb, ao);

  // 5. rmsnorm + act quant
  k_rmsq8<<<NROWS, 256, 0, stream>>>(ao, subln, yq, ys);

  // 6. output i8 GEMM (128x128, 2-wave, single-barrier pipeline)
  k_gemm8<<<512, 128, 0, stream>>>(yq, wqo, out, ys, wsc, 3, NROWS, 4096, 4096);
}